// Round 4
// baseline (1894.529 us; speedup 1.0000x reference)
//
#include <hip/hip_runtime.h>
#include <math.h>

#define BB 64
#define FF 64
#define GG 512
#define NN 16384
#define PTOT (BB*NN)          // 1048576
#define EPSF 1e-6f
#define BN_EPSF 1e-5f

// ws float offsets
#define WS_S1RAW  0           // [2][64] sum h1raw
#define WS_S2RAW  128         // [2][64] sum h1raw^2
#define WS_H2S1   256         // [2][64] sum h2
#define WS_H2S2   384         // [2][64] sum h2^2   (zero region ends at 512)
#define WS_COEF   512         // [2][64][3] -> 896
#define WS_M2     896         // [2][64]
#define WS_RS2    1024        // [2][64] -> 1152
#define WS_FILMW  1280        // [2][64*64] -> 9472
#define WS_FILMB  9472        // [2][64*64] -> 17664
#define WS_ZERO_FLOATS 512

#define OFF_MU  (BB*3*NN)
#define OFF_LV  (2*BB*3*NN)

// ---------------- FiLM (one launch per branch x {cw,cb}); dumb & redundant ----------------
__global__ __launch_bounds__(256) void k_film(const float* __restrict__ g,
                                              const float* __restrict__ W0,
                                              const float* __restrict__ bng,
                                              const float* __restrict__ bnb,
                                              const float* __restrict__ W1,
                                              const float* __restrict__ b1,
                                              float* __restrict__ outp) {
    __shared__ float H[64][65];
    __shared__ float S[64][65];
    const int t = threadIdx.x;
    // phase 1: H[b][f] = g[b,:] . W0[f,:]
    for (int idx = t; idx < 4096; idx += 256) {
        const int b = idx >> 6, f = idx & 63;
        float acc = 0.f;
        for (int k = 0; k < GG; ++k) acc = fmaf(g[b*GG + k], W0[f*GG + k], acc);
        H[b][f] = acc;
    }
    __syncthreads();
    // phase 2: BN over batch per feature f (redundant per-thread two-pass stats), then SiLU
    for (int idx = t; idx < 4096; idx += 256) {
        const int b = idx >> 6, f = idx & 63;
        float m = 0.f;
        for (int b2 = 0; b2 < 64; ++b2) m += H[b2][f];
        m *= (1.f/64.f);
        float v = 0.f;
        for (int b2 = 0; b2 < 64; ++b2) { const float d = H[b2][f] - m; v = fmaf(d, d, v); }
        v *= (1.f/64.f);
        const float xh = (H[b][f] - m) * rsqrtf(v + BN_EPSF) * bng[f] + bnb[f];
        S[b][f] = xh / (1.f + expf(-xh));   // SiLU
    }
    __syncthreads();
    // phase 3: out[b][f2] = S[b,:] . W1[f2,:] + b1[f2]
    for (int idx = t; idx < 4096; idx += 256) {
        const int b = idx >> 6, f2 = idx & 63;
        float acc = 0.f;
        for (int k = 0; k < 64; ++k) acc = fmaf(S[b][k], W1[f2*64 + k], acc);
        outp[b*64 + f2] = acc + b1[f2];
    }
}

// ---------------- direct BN1 stats: sum / sumsq of h1raw = w0*u + w1*v ----------------
__global__ __launch_bounds__(256) void k_h1stats(const float* __restrict__ p,
                                                 const float* __restrict__ lvW,
                                                 const float* __restrict__ muW,
                                                 float* __restrict__ ws) {
    __shared__ float uvi[128][2];
    const int t  = threadIdx.x;
    const int br = blockIdx.y;
    const int start = blockIdx.x * 4096;   // within one batch b
    const int b = start >> 14, nbase = start & 16383;
    const float* pk = p + (size_t)b*3*NN + NN;
    const int c = t & 63, kk = t >> 6;
    const float* W = br ? muW : lvW;
    const float w0 = W[c*2 + 0], w1 = W[c*2 + 1];
    float s1 = 0.f, s2 = 0.f;
    for (int tile = 0; tile < 32; ++tile) {
        __syncthreads();
        const int nb = nbase + tile*128;
        if (t < 128) { uvi[t][0] = pk[nb + t]; uvi[t][1] = pk[NN + nb + t]; }
        __syncthreads();
        for (int k = kk*32; k < kk*32 + 32; ++k) {
            const float h = fmaf(w0, uvi[k][0], w1 * uvi[k][1]);
            s1 += h;
            s2 = fmaf(h, h, s2);
        }
    }
    atomicAdd(&ws[WS_S1RAW + br*64 + c], s1);
    atomicAdd(&ws[WS_S2RAW + br*64 + c], s2);
}

// ---------------- BN1 coefs from direct stats ----------------
__global__ __launch_bounds__(128) void k_coef2(const float* __restrict__ lvW, const float* __restrict__ lvG,
                                               const float* __restrict__ lvB, const float* __restrict__ muW,
                                               const float* __restrict__ muG, const float* __restrict__ muB,
                                               float* __restrict__ ws) {
    const int t = threadIdx.x;
    const int br = t >> 6, c = t & 63;
    const float* W  = br ? muW : lvW;
    const float* Gp = br ? muG : lvG;
    const float* Bp = br ? muB : lvB;
    const float inv = 1.f / (float)PTOT;
    const float m  = ws[WS_S1RAW + br*64 + c] * inv;
    const float e2 = ws[WS_S2RAW + br*64 + c] * inv;
    const float var = e2 - m*m;
    const float rs  = rsqrtf(var + BN_EPSF);
    const float w0 = W[c*2 + 0], w1 = W[c*2 + 1];
    const float ga = Gp[c], be = Bp[c];
    ws[WS_COEF + (br*64+c)*3 + 0] = w0*rs*ga;
    ws[WS_COEF + (br*64+c)*3 + 1] = w1*rs*ga;
    ws[WS_COEF + (br*64+c)*3 + 2] = be - m*rs*ga;
}

// ---------------- direct BN2 stats: recompute h1 -> h2, accumulate sum / sumsq ----------------
__global__ __launch_bounds__(256) void k_h2stats(const float* __restrict__ p,
                                                 const float* __restrict__ lvW1,
                                                 const float* __restrict__ muW1,
                                                 float* __restrict__ ws) {
    __shared__ float uvi[128][2];
    __shared__ float h1t[128][64];   // [pos][ch], post BN+relu
    __shared__ float Wl[64][64];     // Wl[c][i] = sd1_W[c,i]
    const int t  = threadIdx.x;
    const int br = blockIdx.y;
    const int start = blockIdx.x * 4096;
    const int b = start >> 14, nbase = start & 16383;
    const float* pk = p + (size_t)b*3*NN + NN;
    const int c = t & 63, kk = t >> 6;

    {
        const float* Wsrc = br ? muW1 : lvW1;
        for (int e = t; e < 4096; e += 256) Wl[e >> 6][e & 63] = Wsrc[e];
    }
    const float A0 = ws[WS_COEF + (br*64 + c)*3 + 0];
    const float A1 = ws[WS_COEF + (br*64 + c)*3 + 1];
    const float C0 = ws[WS_COEF + (br*64 + c)*3 + 2];
    __syncthreads();
    float4 wreg[16];
#pragma unroll
    for (int i4 = 0; i4 < 16; ++i4) wreg[i4] = *(const float4*)&Wl[c][i4*4];

    float s1 = 0.f, s2 = 0.f;
    for (int tile = 0; tile < 32; ++tile) {
        __syncthreads();
        const int nb = nbase + tile*128;
        if (t < 128) { uvi[t][0] = pk[nb + t]; uvi[t][1] = pk[NN + nb + t]; }
        __syncthreads();
        for (int k = kk*32; k < kk*32 + 32; ++k)
            h1t[k][c] = fmaxf(fmaf(A0, uvi[k][0], fmaf(A1, uvi[k][1], C0)), 0.f);
        __syncthreads();
        for (int k = kk*32; k < kk*32 + 32; ++k) {
            float acc = 0.f;
#pragma unroll
            for (int i4 = 0; i4 < 16; ++i4) {
                const float4 hv = *(const float4*)&h1t[k][i4*4];
                const float4 wv = wreg[i4];
                acc = fmaf(wv.x, hv.x, acc);
                acc = fmaf(wv.y, hv.y, acc);
                acc = fmaf(wv.z, hv.z, acc);
                acc = fmaf(wv.w, hv.w, acc);
            }
            s1 += acc;
            s2 = fmaf(acc, acc, s2);
        }
    }
    atomicAdd(&ws[WS_H2S1 + br*64 + c], s1);
    atomicAdd(&ws[WS_H2S2 + br*64 + c], s2);
}

// ---------------- finalize BN2 stats ----------------
__global__ __launch_bounds__(128) void k_finstats(float* __restrict__ ws) {
    const int t = threadIdx.x;
    const float inv = 1.f / (float)PTOT;
    const float m2 = ws[WS_H2S1 + t] * inv;
    const float e2 = ws[WS_H2S2 + t] * inv;
    ws[WS_M2  + t] = m2;
    ws[WS_RS2 + t] = rsqrtf(e2 - m2*m2 + BN_EPSF);
}

// ---------------- main pass: thread-per-position ----------------
__global__ __launch_bounds__(256) void k_main(
    const float* __restrict__ p,
    const float* __restrict__ lv_sd1W, const float* __restrict__ mu_sd1W,
    const float* __restrict__ lv_sd2W, const float* __restrict__ lv_sd2b,
    const float* __restrict__ mu_sd2W, const float* __restrict__ mu_sd2b,
    const float* __restrict__ ws, float* __restrict__ out)
{
    __shared__ float W_l[2][64][64];
    __shared__ float cf_l[2][64][3];
    __shared__ float sp_l[2][64], tq_l[2][64], w2_l[2][64];

    const int t  = threadIdx.x;
    const int b0 = (int)((blockIdx.x * 256u) >> 14);

    {
        float4* dst = (float4*)&W_l[0][0][0];
        for (int e = t; e < 2048; e += 256) {
            const int brx = e >> 10, rem = e & 1023;
            dst[e] = ((const float4*)(brx ? mu_sd1W : lv_sd1W))[rem];
        }
    }
    for (int e = t; e < 384; e += 256) (&cf_l[0][0][0])[e] = ws[WS_COEF + e];
    if (t < 128) {
        const int br = t >> 6, c = t & 63;
        const float w   = ws[WS_FILMW + br*4096 + b0*64 + c];
        const float bf  = ws[WS_FILMB + br*4096 + b0*64 + c];
        const float rs2 = ws[WS_RS2 + br*64 + c];
        const float m2  = ws[WS_M2  + br*64 + c];
        const float s = (EPSF + expf(w)) * rs2;
        sp_l[br][c] = s;
        tq_l[br][c] = bf - s * m2;
        w2_l[br][c] = (br ? mu_sd2W : lv_sd2W)[c];
    }
    __syncthreads();

    const int pos = blockIdx.x * 256 + t;
    const int b = pos >> 14, n = pos & 16383;
    const size_t pb = (size_t)b * 3 * NN;
    const float x0 = p[pb + n];
    const float u  = p[pb + NN + n];
    const float v  = p[pb + 2*NN + n];

    float res[2];
#pragma unroll
    for (int br = 0; br < 2; ++br) {
        float h1[64];
#pragma unroll
        for (int i = 0; i < 64; ++i)
            h1[i] = fmaxf(fmaf(cf_l[br][i][0], u, fmaf(cf_l[br][i][1], v, cf_l[br][i][2])), 0.f);
        float acc = 0.f;
#pragma unroll 2
        for (int c = 0; c < 64; ++c) {
            float s_ = 0.f;
#pragma unroll
            for (int i4 = 0; i4 < 16; ++i4) {
                const float4 wv = *(const float4*)&W_l[br][c][i4*4];
                s_ = fmaf(wv.x, h1[i4*4+0], s_);
                s_ = fmaf(wv.y, h1[i4*4+1], s_);
                s_ = fmaf(wv.z, h1[i4*4+2], s_);
                s_ = fmaf(wv.w, h1[i4*4+3], s_);
            }
            const float hf = fmaf(s_, sp_l[br][c], tq_l[br][c]);
            acc = fmaf(fmaxf(hf, 0.f), w2_l[br][c], acc);
        }
        res[br] = acc;
    }
    const float olv = res[0] + lv_sd2b[0];
    const float omu = res[1] + mu_sd2b[0];

    const float lw = olv / (1.f + fabsf(olv));   // softsign
    const float sc = sqrtf(EPSF + expf(lw));
    const float S1 = sqrtf(1.f + EPSF);

    out[pb + n]                   = fmaf(sc, x0, omu);
    out[OFF_MU + pb + n]          = omu;
    out[OFF_LV + pb + n]          = lw;
    out[pb + NN + n]              = S1 * u;
    out[OFF_MU + pb + NN + n]     = 0.f;
    out[OFF_LV + pb + NN + n]     = 0.f;
    out[pb + 2*NN + n]            = S1 * v;
    out[OFF_MU + pb + 2*NN + n]   = 0.f;
    out[OFF_LV + pb + 2*NN + n]   = 0.f;
}

extern "C" void kernel_launch(void* const* d_in, const int* in_sizes, int n_in,
                              void* d_out, int out_size, void* d_ws, size_t ws_size,
                              hipStream_t stream) {
    (void)in_sizes; (void)n_in; (void)out_size; (void)ws_size;
    const float* p = (const float*)d_in[0];
    const float* g = (const float*)d_in[1];
#define IN(i) ((const float*)d_in[i])
    float* ws  = (float*)d_ws;
    float* out = (float*)d_out;

    hipMemsetAsync(d_ws, 0, WS_ZERO_FLOATS * sizeof(float), stream);

    // FiLM: lv_cw -> FILMW[0], lv_cb -> FILMB[0], mu_cw -> FILMW[1], mu_cb -> FILMB[1]
    hipLaunchKernelGGL(k_film, dim3(1), dim3(256), 0, stream,
                       g, IN(6),  IN(7),  IN(8),  IN(9),  IN(10), ws + WS_FILMW);
    hipLaunchKernelGGL(k_film, dim3(1), dim3(256), 0, stream,
                       g, IN(11), IN(12), IN(13), IN(14), IN(15), ws + WS_FILMB);
    hipLaunchKernelGGL(k_film, dim3(1), dim3(256), 0, stream,
                       g, IN(22), IN(23), IN(24), IN(25), IN(26), ws + WS_FILMW + 4096);
    hipLaunchKernelGGL(k_film, dim3(1), dim3(256), 0, stream,
                       g, IN(27), IN(28), IN(29), IN(30), IN(31), ws + WS_FILMB + 4096);

    hipLaunchKernelGGL(k_h1stats, dim3(256, 2), dim3(256), 0, stream, p, IN(2), IN(18), ws);
    hipLaunchKernelGGL(k_coef2,   dim3(1),      dim3(128), 0, stream,
                       IN(2), IN(3), IN(4), IN(18), IN(19), IN(20), ws);
    hipLaunchKernelGGL(k_h2stats, dim3(256, 2), dim3(256), 0, stream, p, IN(5), IN(21), ws);
    hipLaunchKernelGGL(k_finstats, dim3(1),     dim3(128), 0, stream, ws);
    hipLaunchKernelGGL(k_main,    dim3(4096),   dim3(256), 0, stream,
                       p, IN(5), IN(21), IN(16), IN(17), IN(32), IN(33), ws, out);
#undef IN
}

// Round 5
// 853.305 us; speedup vs baseline: 2.2202x; 2.2202x over previous
//
#include <hip/hip_runtime.h>
#include <math.h>

#define BB 64
#define FF 64
#define GG 512
#define NN 16384
#define PTOT (BB*NN)          // 1048576
#define EPSF 1e-6f
#define BN_EPSF 1e-5f

// ws float offsets
#define WS_S1RAW  0           // [2][64] sum h1raw
#define WS_S2RAW  128         // [2][64] sum h1raw^2
#define WS_H2S1   256         // [2][64] sum h2
#define WS_H2S2   384         // [2][64] sum h2^2   (zero region ends at 512)
#define WS_COEF   512         // [2][64][3] -> 896
#define WS_M2     896         // [2][64]
#define WS_RS2    1024        // [2][64] -> 1152
#define WS_FILMW  1280        // [2][64*64] -> 9472
#define WS_FILMB  9472        // [2][64*64] -> 17664
#define WS_WT     17664       // [2][64*64] WT[br][i][c] = sd1_W[c][i] -> 25856
#define WS_ZERO_FLOATS 512

#define OFF_MU  (BB*3*NN)
#define OFF_LV  (2*BB*3*NN)

// ---------------- FiLM: one kernel, 4 blocks (branch x {cw,cb}) ----------------
__global__ __launch_bounds__(256) void k_film4(
    const float* __restrict__ g,
    const float* __restrict__ W0_0, const float* __restrict__ bng_0, const float* __restrict__ bnb_0,
    const float* __restrict__ W1_0, const float* __restrict__ b1_0,
    const float* __restrict__ W0_1, const float* __restrict__ bng_1, const float* __restrict__ bnb_1,
    const float* __restrict__ W1_1, const float* __restrict__ b1_1,
    const float* __restrict__ W0_2, const float* __restrict__ bng_2, const float* __restrict__ bnb_2,
    const float* __restrict__ W1_2, const float* __restrict__ b1_2,
    const float* __restrict__ W0_3, const float* __restrict__ bng_3, const float* __restrict__ bnb_3,
    const float* __restrict__ W1_3, const float* __restrict__ b1_3,
    float* __restrict__ ws) {
    __shared__ float H[64][65];
    __shared__ float S[64][65];
    const int blk = blockIdx.x;
    const int t = threadIdx.x;
    const float* W0  = blk==0 ? W0_0  : blk==1 ? W0_1  : blk==2 ? W0_2  : W0_3;
    const float* bng = blk==0 ? bng_0 : blk==1 ? bng_1 : blk==2 ? bng_2 : bng_3;
    const float* bnb = blk==0 ? bnb_0 : blk==1 ? bnb_1 : blk==2 ? bnb_2 : bnb_3;
    const float* W1  = blk==0 ? W1_0  : blk==1 ? W1_1  : blk==2 ? W1_2  : W1_3;
    const float* b1  = blk==0 ? b1_0  : blk==1 ? b1_1  : blk==2 ? b1_2  : b1_3;
    float* outp = ws + ((blk & 1) ? WS_FILMB : WS_FILMW) + (blk >> 1) * 4096;

    // phase 1: H[b][f] = g[b,:] . W0[f,:]  (float4)
    for (int idx = t; idx < 4096; idx += 256) {
        const int b = idx >> 6, f = idx & 63;
        const float4* gr = (const float4*)(g + b * GG);
        const float4* wr = (const float4*)(W0 + f * GG);
        float a0 = 0.f, a1 = 0.f, a2 = 0.f, a3 = 0.f;
#pragma unroll 4
        for (int k = 0; k < GG/4; ++k) {
            const float4 gv = gr[k], wv = wr[k];
            a0 = fmaf(gv.x, wv.x, a0);
            a1 = fmaf(gv.y, wv.y, a1);
            a2 = fmaf(gv.z, wv.z, a2);
            a3 = fmaf(gv.w, wv.w, a3);
        }
        H[b][f] = (a0 + a1) + (a2 + a3);
    }
    __syncthreads();
    // phase 2: BN over batch per feature f (redundant per-thread stats), then SiLU
    for (int idx = t; idx < 4096; idx += 256) {
        const int b = idx >> 6, f = idx & 63;
        float m = 0.f;
        for (int b2 = 0; b2 < 64; ++b2) m += H[b2][f];
        m *= (1.f/64.f);
        float v = 0.f;
        for (int b2 = 0; b2 < 64; ++b2) { const float d = H[b2][f] - m; v = fmaf(d, d, v); }
        v *= (1.f/64.f);
        const float xh = (H[b][f] - m) * rsqrtf(v + BN_EPSF) * bng[f] + bnb[f];
        S[b][f] = xh / (1.f + expf(-xh));   // SiLU
    }
    __syncthreads();
    // phase 3: out[b][f2] = S[b,:] . W1[f2,:] + b1[f2]
    for (int idx = t; idx < 4096; idx += 256) {
        const int b = idx >> 6, f2 = idx & 63;
        float acc = 0.f;
#pragma unroll 8
        for (int k = 0; k < 64; ++k) acc = fmaf(S[b][k], W1[f2*64 + k], acc);
        outp[b*64 + f2] = acc + b1[f2];
    }
}

// ---------------- direct BN1 stats: sum / sumsq of h1raw = w0*u + w1*v ----------------
__global__ __launch_bounds__(256) void k_h1stats(const float* __restrict__ p,
                                                 const float* __restrict__ lvW,
                                                 const float* __restrict__ muW,
                                                 float* __restrict__ ws) {
    __shared__ float uvi[128][2];
    const int t  = threadIdx.x;
    const int br = blockIdx.y;
    const int start = blockIdx.x * 4096;   // within one batch b
    const int b = start >> 14, nbase = start & 16383;
    const float* pk = p + (size_t)b*3*NN + NN;
    const int c = t & 63, kk = t >> 6;
    const float* W = br ? muW : lvW;
    const float w0 = W[c*2 + 0], w1 = W[c*2 + 1];
    float s1 = 0.f, s2 = 0.f;
    for (int tile = 0; tile < 32; ++tile) {
        __syncthreads();
        const int nb = nbase + tile*128;
        if (t < 128) { uvi[t][0] = pk[nb + t]; uvi[t][1] = pk[NN + nb + t]; }
        __syncthreads();
        for (int k = kk*32; k < kk*32 + 32; ++k) {
            const float h = fmaf(w0, uvi[k][0], w1 * uvi[k][1]);
            s1 += h;
            s2 = fmaf(h, h, s2);
        }
    }
    atomicAdd(&ws[WS_S1RAW + br*64 + c], s1);
    atomicAdd(&ws[WS_S2RAW + br*64 + c], s2);
}

// ---------------- BN1 coefs from direct stats; also build transposed WT ----------------
__global__ __launch_bounds__(128) void k_coef2(const float* __restrict__ lvW, const float* __restrict__ lvG,
                                               const float* __restrict__ lvB, const float* __restrict__ muW,
                                               const float* __restrict__ muG, const float* __restrict__ muB,
                                               const float* __restrict__ lvW1, const float* __restrict__ muW1,
                                               float* __restrict__ ws) {
    const int t = threadIdx.x;
    const int br = t >> 6, c = t & 63;
    const float* W  = br ? muW : lvW;
    const float* Gp = br ? muG : lvG;
    const float* Bp = br ? muB : lvB;
    const float inv = 1.f / (float)PTOT;
    const float m  = ws[WS_S1RAW + br*64 + c] * inv;
    const float e2 = ws[WS_S2RAW + br*64 + c] * inv;
    const float var = e2 - m*m;
    const float rs  = rsqrtf(var + BN_EPSF);
    const float w0 = W[c*2 + 0], w1 = W[c*2 + 1];
    const float ga = Gp[c], be = Bp[c];
    ws[WS_COEF + (br*64+c)*3 + 0] = w0*rs*ga;
    ws[WS_COEF + (br*64+c)*3 + 1] = w1*rs*ga;
    ws[WS_COEF + (br*64+c)*3 + 2] = be - m*rs*ga;
    // transposed WT[br][i][c] = sd1_W[c][i]
    for (int e = t; e < 8192; e += 128) {
        const int brx = e >> 12, r = e & 4095, i = r >> 6, cc = r & 63;
        ws[WS_WT + brx*4096 + i*64 + cc] = (brx ? muW1 : lvW1)[cc*64 + i];
    }
}

// ---------------- BN2 stats: tiled h2 recompute, 4ch x 8pos register tiles ----------------
__global__ __launch_bounds__(256) void k_h2stats(const float* __restrict__ p, float* __restrict__ ws) {
    __shared__ __align__(16) float h1T[64][132];   // [ch][pos]; rows 16B-aligned (132*4=528)
    __shared__ float uvi[128][2];
    __shared__ __align__(16) float cfl[64][4];
    __shared__ __align__(16) float Wl[4096];       // WT linear: [i*64 + c]
    const int t  = threadIdx.x;
    const int br = blockIdx.y;
    const int seg = blockIdx.x * 2048;             // 2048 positions, within one b
    const int b = seg >> 14, nb0 = seg & 16383;
    const float* pk = p + (size_t)b*3*NN + NN;

    if (t < 64) {
        const float* cf = ws + WS_COEF + (br*64 + t)*3;
        cfl[t][0] = cf[0]; cfl[t][1] = cf[1]; cfl[t][2] = cf[2]; cfl[t][3] = 0.f;
    }
    {
        const float4* src = (const float4*)(ws + WS_WT + br*4096);
        float4* dst = (float4*)Wl;
        for (int e = t; e < 1024; e += 256) dst[e] = src[e];
    }
    const int tc = t >> 4, tp8 = t & 15;
    const int c0 = tc*4, p0 = tp8*8;
    const int pos = t & 127, cg = t >> 7;

    float s1[4] = {0.f,0.f,0.f,0.f}, s2[4] = {0.f,0.f,0.f,0.f};

    for (int tile = 0; tile < 16; ++tile) {
        const int nb = nb0 + tile*128;
        __syncthreads();
        if (t < 128) { uvi[t][0] = pk[nb + t]; uvi[t][1] = pk[NN + nb + t]; }
        __syncthreads();
        {
            const float u = uvi[pos][0], v = uvi[pos][1];
#pragma unroll 8
            for (int ci = 0; ci < 32; ++ci) {
                const int c = cg*32 + ci;
                const float4 cf = *(const float4*)&cfl[c][0];
                h1T[c][pos] = fmaxf(fmaf(cf.x, u, fmaf(cf.y, v, cf.z)), 0.f);
            }
        }
        __syncthreads();
        float acc[4][8];
#pragma unroll
        for (int i = 0; i < 4; ++i)
#pragma unroll
            for (int j = 0; j < 8; ++j) acc[i][j] = 0.f;
#pragma unroll 4
        for (int i = 0; i < 64; ++i) {
            const float4 wv = *(const float4*)&Wl[i*64 + c0];
            const float4 h0 = *(const float4*)&h1T[i][p0];
            const float4 h4 = *(const float4*)&h1T[i][p0+4];
            const float hv[8]  = {h0.x,h0.y,h0.z,h0.w,h4.x,h4.y,h4.z,h4.w};
            const float wvv[4] = {wv.x,wv.y,wv.z,wv.w};
#pragma unroll
            for (int cc = 0; cc < 4; ++cc)
#pragma unroll
                for (int pp = 0; pp < 8; ++pp)
                    acc[cc][pp] = fmaf(wvv[cc], hv[pp], acc[cc][pp]);
        }
#pragma unroll
        for (int cc = 0; cc < 4; ++cc) {
#pragma unroll
            for (int pp = 0; pp < 8; ++pp) {
                s1[cc] += acc[cc][pp];
                s2[cc] = fmaf(acc[cc][pp], acc[cc][pp], s2[cc]);
            }
        }
    }
    // block reduce over tp8 (16 partials per channel), red overlaid on h1T rows
    float* red = &h1T[0][0];   // stride 132, rows 0..15 used
    __syncthreads();
#pragma unroll
    for (int cc = 0; cc < 4; ++cc) red[tp8*132 + c0 + cc] = s1[cc];
    __syncthreads();
    if (t < 64) {
        float r = 0.f;
#pragma unroll
        for (int q = 0; q < 16; ++q) r += red[q*132 + t];
        atomicAdd(&ws[WS_H2S1 + br*64 + t], r);
    }
    __syncthreads();
#pragma unroll
    for (int cc = 0; cc < 4; ++cc) red[tp8*132 + c0 + cc] = s2[cc];
    __syncthreads();
    if (t < 64) {
        float r = 0.f;
#pragma unroll
        for (int q = 0; q < 16; ++q) r += red[q*132 + t];
        atomicAdd(&ws[WS_H2S2 + br*64 + t], r);
    }
}

// ---------------- finalize BN2 stats ----------------
__global__ __launch_bounds__(128) void k_finstats(float* __restrict__ ws) {
    const int t = threadIdx.x;
    const float inv = 1.f / (float)PTOT;
    const float m2 = ws[WS_H2S1 + t] * inv;
    const float e2 = ws[WS_H2S2 + t] * inv;
    ws[WS_M2  + t] = m2;
    ws[WS_RS2 + t] = rsqrtf(e2 - m2*m2 + BN_EPSF);
}

// ---------------- main pass: 4ch x 8pos register-tiled GEMM + fused epilogue ----------------
__global__ __launch_bounds__(256) void k_main(
    const float* __restrict__ p,
    const float* __restrict__ lv_sd2W, const float* __restrict__ lv_sd2b,
    const float* __restrict__ mu_sd2W, const float* __restrict__ mu_sd2b,
    const float* __restrict__ ws, float* __restrict__ out)
{
    __shared__ __align__(16) float h1T[64][132];
    __shared__ float uvi[128][2];
    __shared__ __align__(16) float cfl[2][64][4];
    __shared__ __align__(16) float pcl[2][64][4];   // s, t, w2, pad
    __shared__ float outb[2][128];

    const int t   = threadIdx.x;
    const int bid = blockIdx.x;
    const int b   = bid >> 7;
    const int n0  = (bid & 127) * 128;
    const size_t pb = (size_t)b * 3 * NN;

    if (t < 128) {
        const int br = t >> 6, c = t & 63;
        const float* cf = ws + WS_COEF + (br*64 + c)*3;
        cfl[br][c][0] = cf[0]; cfl[br][c][1] = cf[1]; cfl[br][c][2] = cf[2]; cfl[br][c][3] = 0.f;
        const float w   = ws[WS_FILMW + br*4096 + b*64 + c];
        const float bf  = ws[WS_FILMB + br*4096 + b*64 + c];
        const float rs2 = ws[WS_RS2 + br*64 + c];
        const float m2  = ws[WS_M2  + br*64 + c];
        const float s = (EPSF + expf(w)) * rs2;
        pcl[br][c][0] = s;
        pcl[br][c][1] = bf - s * m2;
        pcl[br][c][2] = (br ? mu_sd2W : lv_sd2W)[c];
        pcl[br][c][3] = 0.f;
        uvi[t][0] = p[pb + NN + n0 + t];
        uvi[t][1] = p[pb + 2*NN + n0 + t];
    }

    const int tc = t >> 4, tp8 = t & 15;
    const int c0 = tc*4, p0 = tp8*8;
    const int pos = t & 127, cg = t >> 7;
    const float sd2b0 = lv_sd2b[0], sd2b1 = mu_sd2b[0];

#pragma unroll 1
    for (int br = 0; br < 2; ++br) {
        __syncthreads();
        {
            const float u = uvi[pos][0], v = uvi[pos][1];
#pragma unroll 8
            for (int ci = 0; ci < 32; ++ci) {
                const int c = cg*32 + ci;
                const float4 cf = *(const float4*)&cfl[br][c][0];
                h1T[c][pos] = fmaxf(fmaf(cf.x, u, fmaf(cf.y, v, cf.z)), 0.f);
            }
        }
        __syncthreads();
        float acc[4][8];
#pragma unroll
        for (int i = 0; i < 4; ++i)
#pragma unroll
            for (int j = 0; j < 8; ++j) acc[i][j] = 0.f;
        const float* WT = ws + WS_WT + br*4096;
#pragma unroll 4
        for (int i = 0; i < 64; ++i) {
            const float4 wv = *(const float4*)(WT + i*64 + c0);   // L1-hot global
            const float4 h0 = *(const float4*)&h1T[i][p0];
            const float4 h4 = *(const float4*)&h1T[i][p0+4];
            const float hv[8]  = {h0.x,h0.y,h0.z,h0.w,h4.x,h4.y,h4.z,h4.w};
            const float wvv[4] = {wv.x,wv.y,wv.z,wv.w};
#pragma unroll
            for (int cc = 0; cc < 4; ++cc)
#pragma unroll
                for (int pp = 0; pp < 8; ++pp)
                    acc[cc][pp] = fmaf(wvv[cc], hv[pp], acc[cc][pp]);
        }
        // epilogue: affine + relu + sd2 partial dot over this thread's 4 channels
        float pout[8] = {0.f,0.f,0.f,0.f,0.f,0.f,0.f,0.f};
#pragma unroll
        for (int cc = 0; cc < 4; ++cc) {
            const int c = c0 + cc;
            const float4 pc = *(const float4*)&pcl[br][c][0];
#pragma unroll
            for (int pp = 0; pp < 8; ++pp) {
                const float hf = fmaf(acc[cc][pp], pc.x, pc.y);
                pout[pp] = fmaf(fmaxf(hf, 0.f), pc.z, pout[pp]);
            }
        }
        // reduce over the 16 tc-threads, red overlaid on h1T rows (stride 132)
        float* red = &h1T[0][0];
        __syncthreads();
#pragma unroll
        for (int pp = 0; pp < 8; ++pp) red[tc*132 + p0 + pp] = pout[pp];
        __syncthreads();
        if (t < 128) {
            float sr = 0.f;
#pragma unroll
            for (int q = 0; q < 16; ++q) sr += red[q*132 + t];
            outb[br][t] = sr + (br ? sd2b1 : sd2b0);
        }
    }
    __syncthreads();
    // channels 1,2 pass-through
    {
        const int ch = 1 + (t >> 7), j = t & 127;
        const size_t nix = pb + (size_t)ch*NN + n0 + j;
        const float S1 = sqrtf(1.f + EPSF);
        out[nix]          = S1 * uvi[j][ch-1];
        out[OFF_MU + nix] = 0.f;
        out[OFF_LV + nix] = 0.f;
    }
    // channel 0
    if (t < 128) {
        const size_t nix = pb + n0 + t;
        const float ol = outb[0][t], om = outb[1][t];
        const float lw = ol / (1.f + fabsf(ol));
        const float sc = sqrtf(EPSF + expf(lw));
        out[nix]          = fmaf(sc, p[nix], om);
        out[OFF_MU + nix] = om;
        out[OFF_LV + nix] = lw;
    }
}

extern "C" void kernel_launch(void* const* d_in, const int* in_sizes, int n_in,
                              void* d_out, int out_size, void* d_ws, size_t ws_size,
                              hipStream_t stream) {
    (void)in_sizes; (void)n_in; (void)out_size; (void)ws_size;
    const float* p = (const float*)d_in[0];
    const float* g = (const float*)d_in[1];
#define IN(i) ((const float*)d_in[i])
    float* ws  = (float*)d_ws;
    float* out = (float*)d_out;

    hipMemsetAsync(d_ws, 0, WS_ZERO_FLOATS * sizeof(float), stream);

    // blk0: lv_cw -> FILMW[0]; blk1: lv_cb -> FILMB[0]; blk2: mu_cw -> FILMW[1]; blk3: mu_cb -> FILMB[1]
    hipLaunchKernelGGL(k_film4, dim3(4), dim3(256), 0, stream, g,
                       IN(6),  IN(7),  IN(8),  IN(9),  IN(10),
                       IN(11), IN(12), IN(13), IN(14), IN(15),
                       IN(22), IN(23), IN(24), IN(25), IN(26),
                       IN(27), IN(28), IN(29), IN(30), IN(31),
                       ws);
    hipLaunchKernelGGL(k_h1stats, dim3(256, 2), dim3(256), 0, stream, p, IN(2), IN(18), ws);
    hipLaunchKernelGGL(k_coef2,   dim3(1),      dim3(128), 0, stream,
                       IN(2), IN(3), IN(4), IN(18), IN(19), IN(20), IN(5), IN(21), ws);
    hipLaunchKernelGGL(k_h2stats, dim3(512, 2), dim3(256), 0, stream, p, ws);
    hipLaunchKernelGGL(k_finstats, dim3(1),     dim3(128), 0, stream, ws);
    hipLaunchKernelGGL(k_main,    dim3(8192),   dim3(256), 0, stream,
                       p, IN(16), IN(17), IN(32), IN(33), ws, out);
#undef IN
}

// Round 7
// 580.402 us; speedup vs baseline: 3.2642x; 1.4702x over previous
//
#include <hip/hip_runtime.h>
#include <math.h>

#define BB 64
#define FF 64
#define GG 512
#define NN 16384
#define PTOT (BB*NN)          // 1048576
#define EPSF 1e-6f
#define BN_EPSF 1e-5f

// ws float offsets
#define WS_HBUF   0           // [4][4096] film phase-1 partials (zeroed)
#define WS_S1RAW  16384       // [2][64]
#define WS_S2RAW  16512       // [2][64]
#define WS_H2S1   16640       // [2][64]
#define WS_H2S2   16768       // [2][64]  (zero region ends 16896)
#define WS_COEF   16896       // [2][64][3] -> 17280
#define WS_M2     17280       // [2][64]
#define WS_RS2    17408       // [2][64] -> 17536
#define WS_FILMW  17536       // [2][64*64] -> 25728
#define WS_FILMB  25728       // [2][64*64] -> 33920
#define WS_WT     33920       // [2][64*64] WT[br][i][c] = sd1_W[c][i] -> 42112
#define WS_ZERO_FLOATS 16896

#define OFF_MU  (BB*3*NN)
#define OFF_LV  (2*BB*3*NN)

// ---------------- FiLM phase 1: H_partial = g[:,kc] @ W0[:,kc]^T, K-split ----------------
__global__ __launch_bounds__(256) void k_filmA(
    const float* __restrict__ g,
    const float* __restrict__ W0_0, const float* __restrict__ W0_1,
    const float* __restrict__ W0_2, const float* __restrict__ W0_3,
    float* __restrict__ ws) {
    __shared__ float g_tile[64][65];
    __shared__ float wT[64][69];
    const int combo = blockIdx.x;
    const int kbase = blockIdx.y * 64;
    const int t = threadIdx.x;
    const float* W0 = combo==0 ? W0_0 : combo==1 ? W0_1 : combo==2 ? W0_2 : W0_3;
    float* hb = ws + WS_HBUF + combo*4096;

    // stage g[0:64][kbase:kbase+64] and W0 transposed, coalesced float4
#pragma unroll
    for (int n = 0; n < 4; ++n) {
        const int idx = t + n*256;             // 0..1023 float4s
        const int row = idx >> 4, k4 = idx & 15;
        const float4 gv = *(const float4*)(g  + row*GG + kbase + k4*4);
        const float4 wv = *(const float4*)(W0 + row*GG + kbase + k4*4);
        g_tile[row][k4*4+0] = gv.x; g_tile[row][k4*4+1] = gv.y;
        g_tile[row][k4*4+2] = gv.z; g_tile[row][k4*4+3] = gv.w;
        wT[k4*4+0][row] = wv.x; wT[k4*4+1][row] = wv.y;
        wT[k4*4+2][row] = wv.z; wT[k4*4+3][row] = wv.w;
    }
    __syncthreads();

    const int b0 = (t >> 3) * 2, f0 = (t & 7) * 8;
    float acc[2][8];
#pragma unroll
    for (int i = 0; i < 2; ++i)
#pragma unroll
        for (int j = 0; j < 8; ++j) acc[i][j] = 0.f;
#pragma unroll 4
    for (int k = 0; k < 64; ++k) {
        const float g0 = g_tile[b0][k], g1 = g_tile[b0+1][k];
        const float4 w01 = *(const float4*)&wT[k][f0];
        const float4 w23 = *(const float4*)&wT[k][f0+4];
        const float wv[8] = {w01.x,w01.y,w01.z,w01.w,w23.x,w23.y,w23.z,w23.w};
#pragma unroll
        for (int j = 0; j < 8; ++j) {
            acc[0][j] = fmaf(g0, wv[j], acc[0][j]);
            acc[1][j] = fmaf(g1, wv[j], acc[1][j]);
        }
    }
#pragma unroll
    for (int i = 0; i < 2; ++i)
#pragma unroll
        for (int j = 0; j < 8; ++j)
            atomicAdd(&hb[(b0+i)*64 + f0+j], acc[i][j]);
}

// ---------------- FiLM phase 2+3: BN + SiLU + h @ W1^T + b1 ----------------
__global__ __launch_bounds__(256) void k_filmB(
    const float* __restrict__ bng_0, const float* __restrict__ bnb_0,
    const float* __restrict__ W1_0,  const float* __restrict__ b1_0,
    const float* __restrict__ bng_1, const float* __restrict__ bnb_1,
    const float* __restrict__ W1_1,  const float* __restrict__ b1_1,
    const float* __restrict__ bng_2, const float* __restrict__ bnb_2,
    const float* __restrict__ W1_2,  const float* __restrict__ b1_2,
    const float* __restrict__ bng_3, const float* __restrict__ bnb_3,
    const float* __restrict__ W1_3,  const float* __restrict__ b1_3,
    float* __restrict__ ws) {
    __shared__ float H[64][65];
    __shared__ float S[64][65];
    __shared__ float W1T[64][69];
    const int combo = blockIdx.x;
    const int t = threadIdx.x;
    const float* bng = combo==0 ? bng_0 : combo==1 ? bng_1 : combo==2 ? bng_2 : bng_3;
    const float* bnb = combo==0 ? bnb_0 : combo==1 ? bnb_1 : combo==2 ? bnb_2 : bnb_3;
    const float* W1  = combo==0 ? W1_0  : combo==1 ? W1_1  : combo==2 ? W1_2  : W1_3;
    const float* b1  = combo==0 ? b1_0  : combo==1 ? b1_1  : combo==2 ? b1_2  : b1_3;
    const float* hb  = ws + WS_HBUF + combo*4096;
    float* outp = ws + ((combo & 1) ? WS_FILMB : WS_FILMW) + (combo >> 1) * 4096;

    for (int idx = t; idx < 4096; idx += 256) H[idx >> 6][idx & 63] = hb[idx];
    {   // stage W1 transposed (W1 is 64x64: row = idx>>4, col4 = idx&15)
#pragma unroll
        for (int n = 0; n < 4; ++n) {
            const int idx = t + n*256;          // 0..1023 float4s
            const int f2 = idx >> 4, k4 = idx & 15;
            const float4 wv = *(const float4*)(W1 + f2*64 + k4*4);
            W1T[k4*4+0][f2] = wv.x; W1T[k4*4+1][f2] = wv.y;
            W1T[k4*4+2][f2] = wv.z; W1T[k4*4+3][f2] = wv.w;
        }
    }
    __syncthreads();
    // BN over batch per feature f (redundant per-thread stats), then SiLU
    for (int idx = t; idx < 4096; idx += 256) {
        const int b = idx >> 6, f = idx & 63;
        float m = 0.f;
        for (int b2 = 0; b2 < 64; ++b2) m += H[b2][f];
        m *= (1.f/64.f);
        float v = 0.f;
        for (int b2 = 0; b2 < 64; ++b2) { const float d = H[b2][f] - m; v = fmaf(d, d, v); }
        v *= (1.f/64.f);
        const float xh = (H[b][f] - m) * rsqrtf(v + BN_EPSF) * bng[f] + bnb[f];
        S[b][f] = xh / (1.f + expf(-xh));   // SiLU
    }
    __syncthreads();
    // phase 3: out[b][f2] = S[b,:] . W1[f2,:] + b1[f2], 2x8 register tiles
    const int b0 = (t >> 3) * 2, f0 = (t & 7) * 8;
    float acc[2][8];
#pragma unroll
    for (int i = 0; i < 2; ++i)
#pragma unroll
        for (int j = 0; j < 8; ++j) acc[i][j] = 0.f;
#pragma unroll 4
    for (int k = 0; k < 64; ++k) {
        const float s0 = S[b0][k], s1 = S[b0+1][k];
        const float4 w01 = *(const float4*)&W1T[k][f0];
        const float4 w23 = *(const float4*)&W1T[k][f0+4];
        const float wv[8] = {w01.x,w01.y,w01.z,w01.w,w23.x,w23.y,w23.z,w23.w};
#pragma unroll
        for (int j = 0; j < 8; ++j) {
            acc[0][j] = fmaf(s0, wv[j], acc[0][j]);
            acc[1][j] = fmaf(s1, wv[j], acc[1][j]);
        }
    }
#pragma unroll
    for (int i = 0; i < 2; ++i)
#pragma unroll
        for (int j = 0; j < 8; ++j)
            outp[(b0+i)*64 + f0+j] = acc[i][j] + b1[f0+j];
}

// ---------------- BN1 stats, both branches in one pass ----------------
__global__ __launch_bounds__(256) void k_h1stats(const float* __restrict__ p,
                                                 const float* __restrict__ lvW,
                                                 const float* __restrict__ muW,
                                                 float* __restrict__ ws) {
    __shared__ float uvi[128][2];
    const int t  = threadIdx.x;
    const int start = blockIdx.x * 4096;   // within one batch b
    const int b = start >> 14, nbase = start & 16383;
    const float* pk = p + (size_t)b*3*NN + NN;
    const int c = t & 63, kk = t >> 6;
    const float w0l = lvW[c*2 + 0], w1l = lvW[c*2 + 1];
    const float w0m = muW[c*2 + 0], w1m = muW[c*2 + 1];
    float s1l = 0.f, s2l = 0.f, s1m = 0.f, s2m = 0.f;
    for (int tile = 0; tile < 32; ++tile) {
        __syncthreads();
        const int nb = nbase + tile*128;
        if (t < 128) { uvi[t][0] = pk[nb + t]; uvi[t][1] = pk[NN + nb + t]; }
        __syncthreads();
        for (int k = kk*32; k < kk*32 + 32; ++k) {
            const float u = uvi[k][0], v = uvi[k][1];
            const float hl = fmaf(w0l, u, w1l * v);
            const float hm = fmaf(w0m, u, w1m * v);
            s1l += hl; s2l = fmaf(hl, hl, s2l);
            s1m += hm; s2m = fmaf(hm, hm, s2m);
        }
    }
    atomicAdd(&ws[WS_S1RAW + c],      s1l);
    atomicAdd(&ws[WS_S2RAW + c],      s2l);
    atomicAdd(&ws[WS_S1RAW + 64 + c], s1m);
    atomicAdd(&ws[WS_S2RAW + 64 + c], s2m);
}

// ---------------- BN1 coefs; also build transposed WT ----------------
__global__ __launch_bounds__(128) void k_coef2(const float* __restrict__ lvW, const float* __restrict__ lvG,
                                               const float* __restrict__ lvB, const float* __restrict__ muW,
                                               const float* __restrict__ muG, const float* __restrict__ muB,
                                               const float* __restrict__ lvW1, const float* __restrict__ muW1,
                                               float* __restrict__ ws) {
    const int t = threadIdx.x;
    const int br = t >> 6, c = t & 63;
    const float* W  = br ? muW : lvW;
    const float* Gp = br ? muG : lvG;
    const float* Bp = br ? muB : lvB;
    const float inv = 1.f / (float)PTOT;
    const float m  = ws[WS_S1RAW + br*64 + c] * inv;
    const float e2 = ws[WS_S2RAW + br*64 + c] * inv;
    const float var = e2 - m*m;
    const float rs  = rsqrtf(var + BN_EPSF);
    const float w0 = W[c*2 + 0], w1 = W[c*2 + 1];
    const float ga = Gp[c], be = Bp[c];
    ws[WS_COEF + (br*64+c)*3 + 0] = w0*rs*ga;
    ws[WS_COEF + (br*64+c)*3 + 1] = w1*rs*ga;
    ws[WS_COEF + (br*64+c)*3 + 2] = be - m*rs*ga;
    for (int e = t; e < 8192; e += 128) {
        const int brx = e >> 12, r = e & 4095, i = r >> 6, cc = r & 63;
        ws[WS_WT + brx*4096 + i*64 + cc] = (brx ? muW1 : lvW1)[cc*64 + i];
    }
}

// ---------------- BN2 stats: h2 recompute, 8ch x 8pos register tiles ----------------
__global__ __launch_bounds__(128) void k_h2stats(const float* __restrict__ p, float* __restrict__ ws) {
    __shared__ __align__(16) float h1T[64][132];
    __shared__ float uvi[128][2];
    __shared__ __align__(16) float cfl[64][4];
    const int t  = threadIdx.x;
    const int br = blockIdx.y;
    const int seg = blockIdx.x * 2048;             // 2048 positions, within one b
    const int b = seg >> 14, nb0 = seg & 16383;
    const float* pk = p + (size_t)b*3*NN + NN;
    const float4* WTg = (const float4*)(ws + WS_WT + br*4096);

    if (t < 64) {
        const float* cf = ws + WS_COEF + (br*64 + t)*3;
        cfl[t][0] = cf[0]; cfl[t][1] = cf[1]; cfl[t][2] = cf[2]; cfl[t][3] = 0.f;
    }
    const int tr = t >> 4, tp = t & 15;
    const int c0 = tr*8, p0 = tp*8;

    float s1[8] = {0,0,0,0,0,0,0,0}, s2[8] = {0,0,0,0,0,0,0,0};

    for (int tile = 0; tile < 16; ++tile) {
        const int nb = nb0 + tile*128;
        __syncthreads();
        uvi[t][0] = pk[nb + t];
        uvi[t][1] = pk[NN + nb + t];
        __syncthreads();
        {   // h1T[c][t] for all 64 channels, this thread's position t
            const float u = uvi[t][0], v = uvi[t][1];
#pragma unroll 8
            for (int c = 0; c < 64; ++c) {
                const float4 cf = *(const float4*)&cfl[c][0];
                h1T[c][t] = fmaxf(fmaf(cf.x, u, fmaf(cf.y, v, cf.z)), 0.f);
            }
        }
        __syncthreads();
        float acc[8][8];
#pragma unroll
        for (int i = 0; i < 8; ++i)
#pragma unroll
            for (int j = 0; j < 8; ++j) acc[i][j] = 0.f;
#pragma unroll 2
        for (int i = 0; i < 64; ++i) {
            const float4 w0v = WTg[i*16 + (c0 >> 2)];
            const float4 w1v = WTg[i*16 + (c0 >> 2) + 1];
            const float4 h0 = *(const float4*)&h1T[i][p0];
            const float4 h4 = *(const float4*)&h1T[i][p0+4];
            const float wv[8] = {w0v.x,w0v.y,w0v.z,w0v.w,w1v.x,w1v.y,w1v.z,w1v.w};
            const float hv[8] = {h0.x,h0.y,h0.z,h0.w,h4.x,h4.y,h4.z,h4.w};
#pragma unroll
            for (int cc = 0; cc < 8; ++cc)
#pragma unroll
                for (int pp = 0; pp < 8; ++pp)
                    acc[cc][pp] = fmaf(wv[cc], hv[pp], acc[cc][pp]);
        }
#pragma unroll
        for (int cc = 0; cc < 8; ++cc)
#pragma unroll
            for (int pp = 0; pp < 8; ++pp) {
                s1[cc] += acc[cc][pp];
                s2[cc] = fmaf(acc[cc][pp], acc[cc][pp], s2[cc]);
            }
    }
    // reduce over tp (16 groups) via h1T overlay rows 0..15
    float* red = &h1T[0][0];   // stride 132
    __syncthreads();
#pragma unroll
    for (int cc = 0; cc < 8; ++cc) red[tp*132 + c0 + cc] = s1[cc];
    __syncthreads();
    if (t < 64) {
        float r = 0.f;
#pragma unroll
        for (int q = 0; q < 16; ++q) r += red[q*132 + t];
        atomicAdd(&ws[WS_H2S1 + br*64 + t], r);
    }
    __syncthreads();
#pragma unroll
    for (int cc = 0; cc < 8; ++cc) red[tp*132 + c0 + cc] = s2[cc];
    __syncthreads();
    if (t < 64) {
        float r = 0.f;
#pragma unroll
        for (int q = 0; q < 16; ++q) r += red[q*132 + t];
        atomicAdd(&ws[WS_H2S2 + br*64 + t], r);
    }
}

// ---------------- finalize BN2 stats ----------------
__global__ __launch_bounds__(128) void k_finstats(float* __restrict__ ws) {
    const int t = threadIdx.x;
    const float inv = 1.f / (float)PTOT;
    const float m2 = ws[WS_H2S1 + t] * inv;
    const float e2 = ws[WS_H2S2 + t] * inv;
    ws[WS_M2  + t] = m2;
    ws[WS_RS2 + t] = rsqrtf(e2 - m2*m2 + BN_EPSF);
}

// ---------------- main pass: 8ch x 8pos register-tiled GEMM + fused epilogue ----------------
__global__ __launch_bounds__(128) void k_main(
    const float* __restrict__ p,
    const float* __restrict__ lv_sd2W, const float* __restrict__ lv_sd2b,
    const float* __restrict__ mu_sd2W, const float* __restrict__ mu_sd2b,
    const float* __restrict__ ws, float* __restrict__ out)
{
    __shared__ __align__(16) float h1T[64][132];
    __shared__ float uvi[128][2];
    __shared__ __align__(16) float cfl[2][64][4];
    __shared__ __align__(16) float pcl[2][64][4];   // s, t, w2, pad
    __shared__ float outb[2][128];

    const int t   = threadIdx.x;
    const int bid = blockIdx.x;
    const int b   = bid >> 7;
    const int n0  = (bid & 127) * 128;
    const size_t pb = (size_t)b * 3 * NN;

    {   // per-(br,c) constants; t covers 2x64 exactly
        const int br = t >> 6, c = t & 63;
        const float* cf = ws + WS_COEF + (br*64 + c)*3;
        cfl[br][c][0] = cf[0]; cfl[br][c][1] = cf[1]; cfl[br][c][2] = cf[2]; cfl[br][c][3] = 0.f;
        const float w   = ws[WS_FILMW + br*4096 + b*64 + c];
        const float bf  = ws[WS_FILMB + br*4096 + b*64 + c];
        const float rs2 = ws[WS_RS2 + br*64 + c];
        const float m2  = ws[WS_M2  + br*64 + c];
        const float s = (EPSF + expf(w)) * rs2;
        pcl[br][c][0] = s;
        pcl[br][c][1] = bf - s * m2;
        pcl[br][c][2] = (br ? mu_sd2W : lv_sd2W)[c];
        pcl[br][c][3] = 0.f;
        uvi[t][0] = p[pb + NN + n0 + t];
        uvi[t][1] = p[pb + 2*NN + n0 + t];
    }

    const int tr = t >> 4, tp = t & 15;
    const int c0 = tr*8, p0 = tp*8;
    const float sd2b0 = lv_sd2b[0], sd2b1 = mu_sd2b[0];

#pragma unroll 1
    for (int br = 0; br < 2; ++br) {
        __syncthreads();
        {   // h1T for this branch, thread's position t
            const float u = uvi[t][0], v = uvi[t][1];
#pragma unroll 8
            for (int c = 0; c < 64; ++c) {
                const float4 cf = *(const float4*)&cfl[br][c][0];
                h1T[c][t] = fmaxf(fmaf(cf.x, u, fmaf(cf.y, v, cf.z)), 0.f);
            }
        }
        __syncthreads();
        float acc[8][8];
#pragma unroll
        for (int i = 0; i < 8; ++i)
#pragma unroll
            for (int j = 0; j < 8; ++j) acc[i][j] = 0.f;
        const float4* WTg = (const float4*)(ws + WS_WT + br*4096);
#pragma unroll 2
        for (int i = 0; i < 64; ++i) {
            const float4 w0v = WTg[i*16 + (c0 >> 2)];
            const float4 w1v = WTg[i*16 + (c0 >> 2) + 1];
            const float4 h0 = *(const float4*)&h1T[i][p0];
            const float4 h4 = *(const float4*)&h1T[i][p0+4];
            const float wv[8] = {w0v.x,w0v.y,w0v.z,w0v.w,w1v.x,w1v.y,w1v.z,w1v.w};
            const float hv[8] = {h0.x,h0.y,h0.z,h0.w,h4.x,h4.y,h4.z,h4.w};
#pragma unroll
            for (int cc = 0; cc < 8; ++cc)
#pragma unroll
                for (int pp = 0; pp < 8; ++pp)
                    acc[cc][pp] = fmaf(wv[cc], hv[pp], acc[cc][pp]);
        }
        // epilogue: affine + relu + sd2 partial dot over this thread's 8 channels
        float pout[8] = {0,0,0,0,0,0,0,0};
#pragma unroll
        for (int cc = 0; cc < 8; ++cc) {
            const float4 pc = *(const float4*)&pcl[br][c0+cc][0];
#pragma unroll
            for (int pp = 0; pp < 8; ++pp) {
                const float hf = fmaf(acc[cc][pp], pc.x, pc.y);
                pout[pp] = fmaf(fmaxf(hf, 0.f), pc.z, pout[pp]);
            }
        }
        // reduce over 8 tr-groups via h1T overlay rows 0..7 (barrier: GEMM reads done)
        float* red = &h1T[0][0];
        __syncthreads();
#pragma unroll
        for (int pp = 0; pp < 8; ++pp) red[tr*132 + p0 + pp] = pout[pp];
        __syncthreads();
        {
            float sr = 0.f;
#pragma unroll
            for (int q = 0; q < 8; ++q) sr += red[q*132 + t];
            outb[br][t] = sr + (br ? sd2b1 : sd2b0);
        }
    }
    __syncthreads();
    // channels 1,2 pass-through
    {
        const float S1 = sqrtf(1.f + EPSF);
#pragma unroll
        for (int ch = 1; ch <= 2; ++ch) {
            const size_t nix = pb + (size_t)ch*NN + n0 + t;
            out[nix]          = S1 * uvi[t][ch-1];
            out[OFF_MU + nix] = 0.f;
            out[OFF_LV + nix] = 0.f;
        }
    }
    // channel 0
    {
        const size_t nix = pb + n0 + t;
        const float ol = outb[0][t], om = outb[1][t];
        const float lw = ol / (1.f + fabsf(ol));
        const float sc = sqrtf(EPSF + expf(lw));
        out[nix]          = fmaf(sc, p[nix], om);
        out[OFF_MU + nix] = om;
        out[OFF_LV + nix] = lw;
    }
}

extern "C" void kernel_launch(void* const* d_in, const int* in_sizes, int n_in,
                              void* d_out, int out_size, void* d_ws, size_t ws_size,
                              hipStream_t stream) {
    (void)in_sizes; (void)n_in; (void)out_size; (void)ws_size;
    const float* p = (const float*)d_in[0];
    const float* g = (const float*)d_in[1];
#define IN(i) ((const float*)d_in[i])
    float* ws  = (float*)d_ws;
    float* out = (float*)d_out;

    hipMemsetAsync(d_ws, 0, WS_ZERO_FLOATS * sizeof(float), stream);

    // combos: 0=lv_cw 1=lv_cb 2=mu_cw 3=mu_cb
    hipLaunchKernelGGL(k_filmA, dim3(4, 8), dim3(256), 0, stream,
                       g, IN(6), IN(11), IN(22), IN(27), ws);
    hipLaunchKernelGGL(k_filmB, dim3(4),    dim3(256), 0, stream,
                       IN(7),  IN(8),  IN(9),  IN(10),
                       IN(12), IN(13), IN(14), IN(15),
                       IN(23), IN(24), IN(25), IN(26),
                       IN(28), IN(29), IN(30), IN(31),
                       ws);
    hipLaunchKernelGGL(k_h1stats, dim3(256),    dim3(256), 0, stream, p, IN(2), IN(18), ws);
    hipLaunchKernelGGL(k_coef2,   dim3(1),      dim3(128), 0, stream,
                       IN(2), IN(3), IN(4), IN(18), IN(19), IN(20), IN(5), IN(21), ws);
    hipLaunchKernelGGL(k_h2stats, dim3(512, 2), dim3(128), 0, stream, p, ws);
    hipLaunchKernelGGL(k_finstats, dim3(1),     dim3(128), 0, stream, ws);
    hipLaunchKernelGGL(k_main,    dim3(8192),   dim3(128), 0, stream,
                       p, IN(16), IN(17), IN(32), IN(33), ws, out);
#undef IN
}

// Round 8
// 296.596 us; speedup vs baseline: 6.3876x; 1.9569x over previous
//
#include <hip/hip_runtime.h>
#include <math.h>

#define BB 64
#define FF 64
#define GG 512
#define NN 16384
#define PTOT (BB*NN)          // 1048576
#define EPSF 1e-6f
#define BN_EPSF 1e-5f

// ws float offsets
#define WS_HBUF   0           // [4][4096] film phase-1 partials (zeroed)
#define WS_S1RAW  16384       // [2][64]
#define WS_S2RAW  16512       // [2][64]
#define WS_H2S1   16640       // [2][64]
#define WS_H2S2   16768       // [2][64]  (zero region ends 16896)
#define WS_COEF   16896       // [2][64][3] -> 17280
#define WS_M2     17280       // [2][64]
#define WS_RS2    17408       // [2][64] -> 17536
#define WS_FILMW  17536       // [2][64*64] -> 25728
#define WS_FILMB  25728       // [2][64*64] -> 33920
#define WS_WB     33920       // bf16 W, ushort[2][64][64] = 4096 floats -> 38016
#define WS_ZERO_FLOATS 16896

#define OFF_MU  (BB*3*NN)
#define OFF_LV  (2*BB*3*NN)

typedef __attribute__((ext_vector_type(8))) short short8_t;
typedef __attribute__((ext_vector_type(4))) float f32x4;

__device__ __forceinline__ unsigned int bf16u(float x) {
    unsigned int u = __float_as_uint(x);
    return ((u + 0x7FFFu + ((u >> 16) & 1u)) >> 16) & 0xFFFFu;   // RNE
}

// ---------------- FiLM phase 1: H_partial = g[:,kc] @ W0[:,kc]^T, K-split ----------------
__global__ __launch_bounds__(256) void k_filmA(
    const float* __restrict__ g,
    const float* __restrict__ W0_0, const float* __restrict__ W0_1,
    const float* __restrict__ W0_2, const float* __restrict__ W0_3,
    float* __restrict__ ws) {
    __shared__ float g_tile[64][65];
    __shared__ float wT[64][69];
    const int combo = blockIdx.x;
    const int kbase = blockIdx.y * 64;
    const int t = threadIdx.x;
    const float* W0 = combo==0 ? W0_0 : combo==1 ? W0_1 : combo==2 ? W0_2 : W0_3;
    float* hb = ws + WS_HBUF + combo*4096;

#pragma unroll
    for (int n = 0; n < 4; ++n) {
        const int idx = t + n*256;             // 0..1023 float4s
        const int row = idx >> 4, k4 = idx & 15;
        const float4 gv = *(const float4*)(g  + row*GG + kbase + k4*4);
        const float4 wv = *(const float4*)(W0 + row*GG + kbase + k4*4);
        g_tile[row][k4*4+0] = gv.x; g_tile[row][k4*4+1] = gv.y;
        g_tile[row][k4*4+2] = gv.z; g_tile[row][k4*4+3] = gv.w;
        wT[k4*4+0][row] = wv.x; wT[k4*4+1][row] = wv.y;
        wT[k4*4+2][row] = wv.z; wT[k4*4+3][row] = wv.w;
    }
    __syncthreads();

    const int b0 = (t >> 3) * 2, f0 = (t & 7) * 8;
    float acc[2][8];
#pragma unroll
    for (int i = 0; i < 2; ++i)
#pragma unroll
        for (int j = 0; j < 8; ++j) acc[i][j] = 0.f;
#pragma unroll 4
    for (int k = 0; k < 64; ++k) {
        const float g0 = g_tile[b0][k], g1 = g_tile[b0+1][k];
        const float4 w01 = *(const float4*)&wT[k][f0];
        const float4 w23 = *(const float4*)&wT[k][f0+4];
        const float wv[8] = {w01.x,w01.y,w01.z,w01.w,w23.x,w23.y,w23.z,w23.w};
#pragma unroll
        for (int j = 0; j < 8; ++j) {
            acc[0][j] = fmaf(g0, wv[j], acc[0][j]);
            acc[1][j] = fmaf(g1, wv[j], acc[1][j]);
        }
    }
#pragma unroll
    for (int i = 0; i < 2; ++i)
#pragma unroll
        for (int j = 0; j < 8; ++j)
            atomicAdd(&hb[(b0+i)*64 + f0+j], acc[i][j]);
}

// ---------------- FiLM phase 2+3: BN + SiLU + h @ W1^T + b1 ----------------
__global__ __launch_bounds__(256) void k_filmB(
    const float* __restrict__ bng_0, const float* __restrict__ bnb_0,
    const float* __restrict__ W1_0,  const float* __restrict__ b1_0,
    const float* __restrict__ bng_1, const float* __restrict__ bnb_1,
    const float* __restrict__ W1_1,  const float* __restrict__ b1_1,
    const float* __restrict__ bng_2, const float* __restrict__ bnb_2,
    const float* __restrict__ W1_2,  const float* __restrict__ b1_2,
    const float* __restrict__ bng_3, const float* __restrict__ bnb_3,
    const float* __restrict__ W1_3,  const float* __restrict__ b1_3,
    float* __restrict__ ws) {
    __shared__ float H[64][65];
    __shared__ float S[64][65];
    __shared__ float W1T[64][69];
    const int combo = blockIdx.x;
    const int t = threadIdx.x;
    const float* bng = combo==0 ? bng_0 : combo==1 ? bng_1 : combo==2 ? bng_2 : bng_3;
    const float* bnb = combo==0 ? bnb_0 : combo==1 ? bnb_1 : combo==2 ? bnb_2 : bnb_3;
    const float* W1  = combo==0 ? W1_0  : combo==1 ? W1_1  : combo==2 ? W1_2  : W1_3;
    const float* b1  = combo==0 ? b1_0  : combo==1 ? b1_1  : combo==2 ? b1_2  : b1_3;
    const float* hb  = ws + WS_HBUF + combo*4096;
    float* outp = ws + ((combo & 1) ? WS_FILMB : WS_FILMW) + (combo >> 1) * 4096;

    for (int idx = t; idx < 4096; idx += 256) H[idx >> 6][idx & 63] = hb[idx];
    {   // stage W1 transposed (W1 is 64x64: row = idx>>4, col4 = idx&15)
#pragma unroll
        for (int n = 0; n < 4; ++n) {
            const int idx = t + n*256;          // 0..1023 float4s
            const int f2 = idx >> 4, k4 = idx & 15;
            const float4 wv = *(const float4*)(W1 + f2*64 + k4*4);
            W1T[k4*4+0][f2] = wv.x; W1T[k4*4+1][f2] = wv.y;
            W1T[k4*4+2][f2] = wv.z; W1T[k4*4+3][f2] = wv.w;
        }
    }
    __syncthreads();
    for (int idx = t; idx < 4096; idx += 256) {
        const int b = idx >> 6, f = idx & 63;
        float m = 0.f;
        for (int b2 = 0; b2 < 64; ++b2) m += H[b2][f];
        m *= (1.f/64.f);
        float v = 0.f;
        for (int b2 = 0; b2 < 64; ++b2) { const float d = H[b2][f] - m; v = fmaf(d, d, v); }
        v *= (1.f/64.f);
        const float xh = (H[b][f] - m) * rsqrtf(v + BN_EPSF) * bng[f] + bnb[f];
        S[b][f] = xh / (1.f + expf(-xh));   // SiLU
    }
    __syncthreads();
    const int b0 = (t >> 3) * 2, f0 = (t & 7) * 8;
    float acc[2][8];
#pragma unroll
    for (int i = 0; i < 2; ++i)
#pragma unroll
        for (int j = 0; j < 8; ++j) acc[i][j] = 0.f;
#pragma unroll 4
    for (int k = 0; k < 64; ++k) {
        const float s0 = S[b0][k], s1 = S[b0+1][k];
        const float4 w01 = *(const float4*)&W1T[k][f0];
        const float4 w23 = *(const float4*)&W1T[k][f0+4];
        const float wv[8] = {w01.x,w01.y,w01.z,w01.w,w23.x,w23.y,w23.z,w23.w};
#pragma unroll
        for (int j = 0; j < 8; ++j) {
            acc[0][j] = fmaf(s0, wv[j], acc[0][j]);
            acc[1][j] = fmaf(s1, wv[j], acc[1][j]);
        }
    }
#pragma unroll
    for (int i = 0; i < 2; ++i)
#pragma unroll
        for (int j = 0; j < 8; ++j)
            outp[(b0+i)*64 + f0+j] = acc[i][j] + b1[f0+j];
}

// ---------------- BN1 stats, both branches in one pass ----------------
__global__ __launch_bounds__(256) void k_h1stats(const float* __restrict__ p,
                                                 const float* __restrict__ lvW,
                                                 const float* __restrict__ muW,
                                                 float* __restrict__ ws) {
    __shared__ float uvi[128][2];
    const int t  = threadIdx.x;
    const int start = blockIdx.x * 4096;   // within one batch b
    const int b = start >> 14, nbase = start & 16383;
    const float* pk = p + (size_t)b*3*NN + NN;
    const int c = t & 63, kk = t >> 6;
    const float w0l = lvW[c*2 + 0], w1l = lvW[c*2 + 1];
    const float w0m = muW[c*2 + 0], w1m = muW[c*2 + 1];
    float s1l = 0.f, s2l = 0.f, s1m = 0.f, s2m = 0.f;
    for (int tile = 0; tile < 32; ++tile) {
        __syncthreads();
        const int nb = nbase + tile*128;
        if (t < 128) { uvi[t][0] = pk[nb + t]; uvi[t][1] = pk[NN + nb + t]; }
        __syncthreads();
        for (int k = kk*32; k < kk*32 + 32; ++k) {
            const float u = uvi[k][0], v = uvi[k][1];
            const float hl = fmaf(w0l, u, w1l * v);
            const float hm = fmaf(w0m, u, w1m * v);
            s1l += hl; s2l = fmaf(hl, hl, s2l);
            s1m += hm; s2m = fmaf(hm, hm, s2m);
        }
    }
    atomicAdd(&ws[WS_S1RAW + c],      s1l);
    atomicAdd(&ws[WS_S2RAW + c],      s2l);
    atomicAdd(&ws[WS_S1RAW + 64 + c], s1m);
    atomicAdd(&ws[WS_S2RAW + 64 + c], s2m);
}

// ---------------- BN1 coefs; also build bf16 W ----------------
__global__ __launch_bounds__(128) void k_coef2(const float* __restrict__ lvW, const float* __restrict__ lvG,
                                               const float* __restrict__ lvB, const float* __restrict__ muW,
                                               const float* __restrict__ muG, const float* __restrict__ muB,
                                               const float* __restrict__ lvW1, const float* __restrict__ muW1,
                                               float* __restrict__ ws) {
    const int t = threadIdx.x;
    const int br = t >> 6, c = t & 63;
    const float* W  = br ? muW : lvW;
    const float* Gp = br ? muG : lvG;
    const float* Bp = br ? muB : lvB;
    const float inv = 1.f / (float)PTOT;
    const float m  = ws[WS_S1RAW + br*64 + c] * inv;
    const float e2 = ws[WS_S2RAW + br*64 + c] * inv;
    const float var = e2 - m*m;
    const float rs  = rsqrtf(var + BN_EPSF);
    const float w0 = W[c*2 + 0], w1 = W[c*2 + 1];
    const float ga = Gp[c], be = Bp[c];
    ws[WS_COEF + (br*64+c)*3 + 0] = w0*rs*ga;
    ws[WS_COEF + (br*64+c)*3 + 1] = w1*rs*ga;
    ws[WS_COEF + (br*64+c)*3 + 2] = be - m*rs*ga;
    // bf16 copy of sd1_W, row-major [br][c][k]
    unsigned short* wb = (unsigned short*)(ws + WS_WB);
    for (int e = t; e < 8192; e += 128) {
        const int brx = e >> 12, r = e & 4095;
        wb[e] = (unsigned short)bf16u((brx ? muW1 : lvW1)[r]);
    }
}

// ---------------- BN2 stats: MFMA h2 recompute, accumulate sum/sumsq ----------------
__global__ __launch_bounds__(256) void k_h2stats(const float* __restrict__ p, float* __restrict__ ws) {
    __shared__ __align__(16) unsigned short h1P[128*64];   // bf16 [pos][ch], XOR-swizzled
    __shared__ __align__(16) float cfl[2][64][4];
    const int t = threadIdx.x;
    const int seg = blockIdx.x * 1024;         // 1024 positions per block, within one b
    const int b = seg >> 14, nbase = seg & 16383;
    const float* pk = p + (size_t)b*3*NN + NN;

    if (t < 128) {
        const int br = t >> 6, c = t & 63;
        const float* cf = ws + WS_COEF + (br*64 + c)*3;
        cfl[br][c][0] = cf[0]; cfl[br][c][1] = cf[1]; cfl[br][c][2] = cf[2]; cfl[br][c][3] = 0.f;
    }
    const int w = t >> 6, lane = t & 63, g = lane >> 4, col = lane & 15;
    const unsigned short* wbg = (const unsigned short*)(ws + WS_WB);
    short8_t afr[2][2];
#pragma unroll
    for (int br = 0; br < 2; ++br)
#pragma unroll
        for (int kt = 0; kt < 2; ++kt)
            afr[br][kt] = *(const short8_t*)(wbg + br*4096 + (w*16 + col)*64 + kt*32 + g*8);

    float s1a[2][4], s2a[2][4];
#pragma unroll
    for (int br = 0; br < 2; ++br)
#pragma unroll
        for (int r = 0; r < 4; ++r) { s1a[br][r] = 0.f; s2a[br][r] = 0.f; }

    const int pos = t & 127, cb = (t >> 7) * 32;
    for (int tile = 0; tile < 8; ++tile) {
        const int nb = nbase + tile*128;
        const float u = pk[nb + pos];
        const float v = pk[NN + nb + pos];
#pragma unroll
        for (int br = 0; br < 2; ++br) {
            __syncthreads();   // prior reads of h1P complete
            {   // fill h1P rows (32 ch per thread), swizzled chunks
                unsigned short* hrow = h1P + pos*64;
#pragma unroll
                for (int jj = 0; jj < 4; ++jj) {
                    const int cbase = cb + jj*8;
                    unsigned int dw[4];
#pragma unroll
                    for (int q = 0; q < 4; ++q) {
                        const int c0 = cbase + q*2;
                        const float4 cf0 = *(const float4*)&cfl[br][c0][0];
                        const float4 cf1 = *(const float4*)&cfl[br][c0+1][0];
                        const float h0 = fmaxf(fmaf(cf0.x, u, fmaf(cf0.y, v, cf0.z)), 0.f);
                        const float h1 = fmaxf(fmaf(cf1.x, u, fmaf(cf1.y, v, cf1.z)), 0.f);
                        dw[q] = (bf16u(h1) << 16) | bf16u(h0);
                    }
                    const int chunk = (cbase >> 3) ^ (pos & 7);
                    uint4 vv; vv.x = dw[0]; vv.y = dw[1]; vv.z = dw[2]; vv.w = dw[3];
                    *(uint4*)(hrow + chunk*8) = vv;
                }
            }
            __syncthreads();
            f32x4 acc[8];
#pragma unroll
            for (int n = 0; n < 8; ++n) { f32x4 z = {0.f,0.f,0.f,0.f}; acc[n] = z; }
#pragma unroll
            for (int n = 0; n < 8; ++n) {
                const int row = n*16 + col;
                const short8_t b0 = *(const short8_t*)(h1P + row*64 + ((g ^ (row & 7)) << 3));
                const short8_t b1 = *(const short8_t*)(h1P + row*64 + (((4 + g) ^ (row & 7)) << 3));
                acc[n] = __builtin_amdgcn_mfma_f32_16x16x32_bf16(afr[br][0], b0, acc[n], 0, 0, 0);
                acc[n] = __builtin_amdgcn_mfma_f32_16x16x32_bf16(afr[br][1], b1, acc[n], 0, 0, 0);
            }
#pragma unroll
            for (int n = 0; n < 8; ++n)
#pragma unroll
                for (int r = 0; r < 4; ++r) {
                    const float x = acc[n][r];
                    s1a[br][r] += x;
                    s2a[br][r] = fmaf(x, x, s2a[br][r]);
                }
        }
    }
    // reduce over the 16 p-columns (lanes differing in l&15), then atomics
#pragma unroll
    for (int br = 0; br < 2; ++br)
#pragma unroll
        for (int r = 0; r < 4; ++r) {
            float v1 = s1a[br][r], v2 = s2a[br][r];
#pragma unroll
            for (int off = 1; off <= 8; off <<= 1) {
                v1 += __shfl_xor(v1, off);
                v2 += __shfl_xor(v2, off);
            }
            if (col == 0) {
                const int c = w*16 + g*4 + r;
                atomicAdd(&ws[WS_H2S1 + br*64 + c], v1);
                atomicAdd(&ws[WS_H2S2 + br*64 + c], v2);
            }
        }
}

// ---------------- finalize BN2 stats ----------------
__global__ __launch_bounds__(128) void k_finstats(float* __restrict__ ws) {
    const int t = threadIdx.x;
    const float inv = 1.f / (float)PTOT;
    const float m2 = ws[WS_H2S1 + t] * inv;
    const float e2 = ws[WS_H2S2 + t] * inv;
    ws[WS_M2  + t] = m2;
    ws[WS_RS2 + t] = rsqrtf(e2 - m2*m2 + BN_EPSF);
}

// ---------------- main pass: MFMA GEMM + fused epilogue ----------------
__global__ __launch_bounds__(256) void k_main(
    const float* __restrict__ p,
    const float* __restrict__ lv_sd2W, const float* __restrict__ lv_sd2b,
    const float* __restrict__ mu_sd2W, const float* __restrict__ mu_sd2b,
    const float* __restrict__ ws, float* __restrict__ out)
{
    __shared__ __align__(16) unsigned short h1P[128*64];   // bf16 [pos][ch], XOR-swizzled
    __shared__ float uvi[128][2];
    __shared__ __align__(16) float cfl[2][64][4];
    __shared__ __align__(16) float pcl[2][64][4];          // s, t, w2, pad
    __shared__ float outred[4][128];
    __shared__ float outb[2][128];

    const int t   = threadIdx.x;
    const int bid = blockIdx.x;
    const int b   = bid >> 7;
    const int n0  = (bid & 127) * 128;
    const size_t pb = (size_t)b * 3 * NN;

    if (t < 128) {
        const int br = t >> 6, c = t & 63;
        const float* cf = ws + WS_COEF + (br*64 + c)*3;
        cfl[br][c][0] = cf[0]; cfl[br][c][1] = cf[1]; cfl[br][c][2] = cf[2]; cfl[br][c][3] = 0.f;
        const float fw  = ws[WS_FILMW + br*4096 + b*64 + c];
        const float fb  = ws[WS_FILMB + br*4096 + b*64 + c];
        const float rs2 = ws[WS_RS2 + br*64 + c];
        const float m2  = ws[WS_M2  + br*64 + c];
        const float s = (EPSF + expf(fw)) * rs2;
        pcl[br][c][0] = s;
        pcl[br][c][1] = fb - s * m2;
        pcl[br][c][2] = (br ? mu_sd2W : lv_sd2W)[c];
        pcl[br][c][3] = 0.f;
        uvi[t][0] = p[pb + NN + n0 + t];
        uvi[t][1] = p[pb + 2*NN + n0 + t];
    }
    const int w = t >> 6, lane = t & 63, g = lane >> 4, col = lane & 15;
    const unsigned short* wbg = (const unsigned short*)(ws + WS_WB);
    const float sd2b0 = lv_sd2b[0], sd2b1 = mu_sd2b[0];
    const int pos = t & 127, cb = (t >> 7) * 32;

#pragma unroll 1
    for (int br = 0; br < 2; ++br) {
        __syncthreads();
        {   // fill h1P (bf16, swizzled)
            const float u = uvi[pos][0], v = uvi[pos][1];
            unsigned short* hrow = h1P + pos*64;
#pragma unroll
            for (int jj = 0; jj < 4; ++jj) {
                const int cbase = cb + jj*8;
                unsigned int dw[4];
#pragma unroll
                for (int q = 0; q < 4; ++q) {
                    const int c0 = cbase + q*2;
                    const float4 cf0 = *(const float4*)&cfl[br][c0][0];
                    const float4 cf1 = *(const float4*)&cfl[br][c0+1][0];
                    const float h0 = fmaxf(fmaf(cf0.x, u, fmaf(cf0.y, v, cf0.z)), 0.f);
                    const float h1 = fmaxf(fmaf(cf1.x, u, fmaf(cf1.y, v, cf1.z)), 0.f);
                    dw[q] = (bf16u(h1) << 16) | bf16u(h0);
                }
                const int chunk = (cbase >> 3) ^ (pos & 7);
                uint4 vv; vv.x = dw[0]; vv.y = dw[1]; vv.z = dw[2]; vv.w = dw[3];
                *(uint4*)(hrow + chunk*8) = vv;
            }
        }
        __syncthreads();
        // A-fragments for this wave's m-tile (c = w*16 + col), both k-steps
        const unsigned short* wbb = wbg + br*4096;
        const short8_t a0 = *(const short8_t*)(wbb + (w*16 + col)*64 + g*8);
        const short8_t a1 = *(const short8_t*)(wbb + (w*16 + col)*64 + 32 + g*8);
        f32x4 acc[8];
#pragma unroll
        for (int n = 0; n < 8; ++n) { f32x4 z = {0.f,0.f,0.f,0.f}; acc[n] = z; }
#pragma unroll
        for (int n = 0; n < 8; ++n) {
            const int row = n*16 + col;
            const short8_t b0 = *(const short8_t*)(h1P + row*64 + ((g ^ (row & 7)) << 3));
            const short8_t b1 = *(const short8_t*)(h1P + row*64 + (((4 + g) ^ (row & 7)) << 3));
            acc[n] = __builtin_amdgcn_mfma_f32_16x16x32_bf16(a0, b0, acc[n], 0, 0, 0);
            acc[n] = __builtin_amdgcn_mfma_f32_16x16x32_bf16(a1, b1, acc[n], 0, 0, 0);
        }
        // epilogue: affine + relu + sd2 partial dot over lane's 4 c-rows
        float sr[4], tq[4], w2[4];
#pragma unroll
        for (int r = 0; r < 4; ++r) {
            const float4 pc = *(const float4*)&pcl[br][w*16 + g*4 + r][0];
            sr[r] = pc.x; tq[r] = pc.y; w2[r] = pc.z;
        }
#pragma unroll
        for (int n = 0; n < 8; ++n) {
            float po = 0.f;
#pragma unroll
            for (int r = 0; r < 4; ++r) {
                const float hf = fmaf(acc[n][r], sr[r], tq[r]);
                po = fmaf(fmaxf(hf, 0.f), w2[r], po);
            }
            po += __shfl_xor(po, 16);
            po += __shfl_xor(po, 32);
            if (lane < 16) outred[w][n*16 + lane] = po;
        }
        __syncthreads();
        if (t < 128)
            outb[br][t] = outred[0][t] + outred[1][t] + outred[2][t] + outred[3][t]
                        + (br ? sd2b1 : sd2b0);
    }
    __syncthreads();
    // channels 1,2 pass-through
    {
        const float S1 = sqrtf(1.f + EPSF);
        const int ch = 1 + (t >> 7), j = t & 127;
        const size_t nix = pb + (size_t)ch*NN + n0 + j;
        out[nix]          = S1 * uvi[j][ch-1];
        out[OFF_MU + nix] = 0.f;
        out[OFF_LV + nix] = 0.f;
    }
    // channel 0
    if (t < 128) {
        const size_t nix = pb + n0 + t;
        const float ol = outb[0][t], om = outb[1][t];
        const float lw = ol / (1.f + fabsf(ol));
        const float sc = sqrtf(EPSF + expf(lw));
        out[nix]          = fmaf(sc, p[nix], om);
        out[OFF_MU + nix] = om;
        out[OFF_LV + nix] = lw;
    }
}

extern "C" void kernel_launch(void* const* d_in, const int* in_sizes, int n_in,
                              void* d_out, int out_size, void* d_ws, size_t ws_size,
                              hipStream_t stream) {
    (void)in_sizes; (void)n_in; (void)out_size; (void)ws_size;
    const float* p = (const float*)d_in[0];
    const float* g = (const float*)d_in[1];
#define IN(i) ((const float*)d_in[i])
    float* ws  = (float*)d_ws;
    float* out = (float*)d_out;

    hipMemsetAsync(d_ws, 0, WS_ZERO_FLOATS * sizeof(float), stream);

    // combos: 0=lv_cw 1=lv_cb 2=mu_cw 3=mu_cb
    hipLaunchKernelGGL(k_filmA, dim3(4, 8), dim3(256), 0, stream,
                       g, IN(6), IN(11), IN(22), IN(27), ws);
    hipLaunchKernelGGL(k_filmB, dim3(4),    dim3(256), 0, stream,
                       IN(7),  IN(8),  IN(9),  IN(10),
                       IN(12), IN(13), IN(14), IN(15),
                       IN(23), IN(24), IN(25), IN(26),
                       IN(28), IN(29), IN(30), IN(31),
                       ws);
    hipLaunchKernelGGL(k_h1stats, dim3(256),  dim3(256), 0, stream, p, IN(2), IN(18), ws);
    hipLaunchKernelGGL(k_coef2,   dim3(1),    dim3(128), 0, stream,
                       IN(2), IN(3), IN(4), IN(18), IN(19), IN(20), IN(5), IN(21), ws);
    hipLaunchKernelGGL(k_h2stats, dim3(1024), dim3(256), 0, stream, p, ws);
    hipLaunchKernelGGL(k_finstats, dim3(1),   dim3(128), 0, stream, ws);
    hipLaunchKernelGGL(k_main,    dim3(8192), dim3(256), 0, stream,
                       p, IN(16), IN(17), IN(32), IN(33), ws, out);
#undef IN
}

// Round 9
// 234.800 us; speedup vs baseline: 8.0687x; 1.2632x over previous
//
#include <hip/hip_runtime.h>
#include <math.h>

#define BB 64
#define FF 64
#define GG 512
#define NN 16384
#define PTOT (BB*NN)          // 1048576
#define EPSF 1e-6f
#define BN_EPSF 1e-5f

// ws float offsets
#define WS_HBUF   0           // [4][4096] film phase-1 partials (zeroed)
#define WS_MOM    16384       // 5 moments (Su,Sv,Suu,Svv,Suv) + pad -> 16392
#define WS_H2S1   16392       // [2][64]
#define WS_H2S2   16520       // [2][64]  (zero region ends 16648)
#define WS_COEF   16648       // [2][64][3] -> 17032
#define WS_M2     17032       // [2][64]
#define WS_RS2    17160       // [2][64] -> 17288
#define WS_FILMW  17288       // [2][64*64] -> 25480
#define WS_FILMB  25480       // [2][64*64] -> 33672
#define WS_WB     33672       // bf16 W, ushort[2][64][64] = 4096 floats -> 37768
#define WS_ZERO_FLOATS 16648

#define OFF_MU  (BB*3*NN)
#define OFF_LV  (2*BB*3*NN)

typedef __attribute__((ext_vector_type(8))) short short8_t;
typedef __attribute__((ext_vector_type(4))) float f32x4;

__device__ __forceinline__ unsigned int bf16u(float x) {
    unsigned int u = __float_as_uint(x);
    return ((u + 0x7FFFu + ((u >> 16) & 1u)) >> 16) & 0xFFFFu;   // RNE
}

// ---------------- FiLM phase 1: H_partial = g[:,kc] @ W0[:,kc]^T, K-split ----------------
__global__ __launch_bounds__(256) void k_filmA(
    const float* __restrict__ g,
    const float* __restrict__ W0_0, const float* __restrict__ W0_1,
    const float* __restrict__ W0_2, const float* __restrict__ W0_3,
    float* __restrict__ ws) {
    __shared__ float g_tile[64][65];
    __shared__ float wT[64][69];
    const int combo = blockIdx.x;
    const int kbase = blockIdx.y * 64;
    const int t = threadIdx.x;
    const float* W0 = combo==0 ? W0_0 : combo==1 ? W0_1 : combo==2 ? W0_2 : W0_3;
    float* hb = ws + WS_HBUF + combo*4096;

#pragma unroll
    for (int n = 0; n < 4; ++n) {
        const int idx = t + n*256;             // 0..1023 float4s
        const int row = idx >> 4, k4 = idx & 15;
        const float4 gv = *(const float4*)(g  + row*GG + kbase + k4*4);
        const float4 wv = *(const float4*)(W0 + row*GG + kbase + k4*4);
        g_tile[row][k4*4+0] = gv.x; g_tile[row][k4*4+1] = gv.y;
        g_tile[row][k4*4+2] = gv.z; g_tile[row][k4*4+3] = gv.w;
        wT[k4*4+0][row] = wv.x; wT[k4*4+1][row] = wv.y;
        wT[k4*4+2][row] = wv.z; wT[k4*4+3][row] = wv.w;
    }
    __syncthreads();

    const int b0 = (t >> 3) * 2, f0 = (t & 7) * 8;
    float acc[2][8];
#pragma unroll
    for (int i = 0; i < 2; ++i)
#pragma unroll
        for (int j = 0; j < 8; ++j) acc[i][j] = 0.f;
#pragma unroll 4
    for (int k = 0; k < 64; ++k) {
        const float g0 = g_tile[b0][k], g1 = g_tile[b0+1][k];
        const float4 w01 = *(const float4*)&wT[k][f0];
        const float4 w23 = *(const float4*)&wT[k][f0+4];
        const float wv[8] = {w01.x,w01.y,w01.z,w01.w,w23.x,w23.y,w23.z,w23.w};
#pragma unroll
        for (int j = 0; j < 8; ++j) {
            acc[0][j] = fmaf(g0, wv[j], acc[0][j]);
            acc[1][j] = fmaf(g1, wv[j], acc[1][j]);
        }
    }
#pragma unroll
    for (int i = 0; i < 2; ++i)
#pragma unroll
        for (int j = 0; j < 8; ++j)
            atomicAdd(&hb[(b0+i)*64 + f0+j], acc[i][j]);
}

// ---------------- FiLM phase 2+3: BN + SiLU + h @ W1^T + b1 ----------------
__global__ __launch_bounds__(256) void k_filmB(
    const float* __restrict__ bng_0, const float* __restrict__ bnb_0,
    const float* __restrict__ W1_0,  const float* __restrict__ b1_0,
    const float* __restrict__ bng_1, const float* __restrict__ bnb_1,
    const float* __restrict__ W1_1,  const float* __restrict__ b1_1,
    const float* __restrict__ bng_2, const float* __restrict__ bnb_2,
    const float* __restrict__ W1_2,  const float* __restrict__ b1_2,
    const float* __restrict__ bng_3, const float* __restrict__ bnb_3,
    const float* __restrict__ W1_3,  const float* __restrict__ b1_3,
    float* __restrict__ ws) {
    __shared__ float H[64][65];
    __shared__ float S[64][65];
    __shared__ float W1T[64][69];
    const int combo = blockIdx.x;
    const int t = threadIdx.x;
    const float* bng = combo==0 ? bng_0 : combo==1 ? bng_1 : combo==2 ? bng_2 : bng_3;
    const float* bnb = combo==0 ? bnb_0 : combo==1 ? bnb_1 : combo==2 ? bnb_2 : bnb_3;
    const float* W1  = combo==0 ? W1_0  : combo==1 ? W1_1  : combo==2 ? W1_2  : W1_3;
    const float* b1  = combo==0 ? b1_0  : combo==1 ? b1_1  : combo==2 ? b1_2  : b1_3;
    const float* hb  = ws + WS_HBUF + combo*4096;
    float* outp = ws + ((combo & 1) ? WS_FILMB : WS_FILMW) + (combo >> 1) * 4096;

    for (int idx = t; idx < 4096; idx += 256) H[idx >> 6][idx & 63] = hb[idx];
    {   // stage W1 transposed (W1 is 64x64: row = idx>>4, col4 = idx&15)
#pragma unroll
        for (int n = 0; n < 4; ++n) {
            const int idx = t + n*256;          // 0..1023 float4s
            const int f2 = idx >> 4, k4 = idx & 15;
            const float4 wv = *(const float4*)(W1 + f2*64 + k4*4);
            W1T[k4*4+0][f2] = wv.x; W1T[k4*4+1][f2] = wv.y;
            W1T[k4*4+2][f2] = wv.z; W1T[k4*4+3][f2] = wv.w;
        }
    }
    __syncthreads();
    for (int idx = t; idx < 4096; idx += 256) {
        const int b = idx >> 6, f = idx & 63;
        float m = 0.f;
        for (int b2 = 0; b2 < 64; ++b2) m += H[b2][f];
        m *= (1.f/64.f);
        float v = 0.f;
        for (int b2 = 0; b2 < 64; ++b2) { const float d = H[b2][f] - m; v = fmaf(d, d, v); }
        v *= (1.f/64.f);
        const float xh = (H[b][f] - m) * rsqrtf(v + BN_EPSF) * bng[f] + bnb[f];
        S[b][f] = xh / (1.f + expf(-xh));   // SiLU
    }
    __syncthreads();
    const int b0 = (t >> 3) * 2, f0 = (t & 7) * 8;
    float acc[2][8];
#pragma unroll
    for (int i = 0; i < 2; ++i)
#pragma unroll
        for (int j = 0; j < 8; ++j) acc[i][j] = 0.f;
#pragma unroll 4
    for (int k = 0; k < 64; ++k) {
        const float s0 = S[b0][k], s1 = S[b0+1][k];
        const float4 w01 = *(const float4*)&W1T[k][f0];
        const float4 w23 = *(const float4*)&W1T[k][f0+4];
        const float wv[8] = {w01.x,w01.y,w01.z,w01.w,w23.x,w23.y,w23.z,w23.w};
#pragma unroll
        for (int j = 0; j < 8; ++j) {
            acc[0][j] = fmaf(s0, wv[j], acc[0][j]);
            acc[1][j] = fmaf(s1, wv[j], acc[1][j]);
        }
    }
#pragma unroll
    for (int i = 0; i < 2; ++i)
#pragma unroll
        for (int j = 0; j < 8; ++j)
            outp[(b0+i)*64 + f0+j] = acc[i][j] + b1[f0+j];
}

// ---------------- global moments of (u,v): barrier-light ----------------
__global__ __launch_bounds__(256) void k_moments(const float* __restrict__ p, float* __restrict__ ws) {
    __shared__ float red[4][8];
    const int t = threadIdx.x;
    const int gid = blockIdx.x * 256 + t;      // 131072 threads, 8 pos each
    const int pos8 = gid << 3;
    const int b = pos8 >> 14, n = pos8 & 16383;
    const float* base = p + (size_t)b*3*NN + NN + n;
    const float4 ua = *(const float4*)base;
    const float4 ub = *(const float4*)(base + 4);
    const float4 va = *(const float4*)(base + NN);
    const float4 vb = *(const float4*)(base + NN + 4);
    float su  = (ua.x+ua.y)+(ua.z+ua.w)+(ub.x+ub.y)+(ub.z+ub.w);
    float sv  = (va.x+va.y)+(va.z+va.w)+(vb.x+vb.y)+(vb.z+vb.w);
    float suu = fmaf(ua.x,ua.x, fmaf(ua.y,ua.y, fmaf(ua.z,ua.z, ua.w*ua.w)))
              + fmaf(ub.x,ub.x, fmaf(ub.y,ub.y, fmaf(ub.z,ub.z, ub.w*ub.w)));
    float svv = fmaf(va.x,va.x, fmaf(va.y,va.y, fmaf(va.z,va.z, va.w*va.w)))
              + fmaf(vb.x,vb.x, fmaf(vb.y,vb.y, fmaf(vb.z,vb.z, vb.w*vb.w)));
    float suv = fmaf(ua.x,va.x, fmaf(ua.y,va.y, fmaf(ua.z,va.z, ua.w*va.w)))
              + fmaf(ub.x,vb.x, fmaf(ub.y,vb.y, fmaf(ub.z,vb.z, ub.w*vb.w)));
#pragma unroll
    for (int off = 32; off > 0; off >>= 1) {
        su  += __shfl_down(su,  off);
        sv  += __shfl_down(sv,  off);
        suu += __shfl_down(suu, off);
        svv += __shfl_down(svv, off);
        suv += __shfl_down(suv, off);
    }
    const int w = t >> 6;
    if ((t & 63) == 0) {
        red[w][0] = su; red[w][1] = sv; red[w][2] = suu; red[w][3] = svv; red[w][4] = suv;
    }
    __syncthreads();
    if (t < 5)
        atomicAdd(&ws[WS_MOM + t], red[0][t] + red[1][t] + red[2][t] + red[3][t]);
}

// ---------------- BN1 coefs (closed form from moments); build bf16 W ----------------
__global__ __launch_bounds__(128) void k_coef2(const float* __restrict__ lvW, const float* __restrict__ lvG,
                                               const float* __restrict__ lvB, const float* __restrict__ muW,
                                               const float* __restrict__ muG, const float* __restrict__ muB,
                                               const float* __restrict__ lvW1, const float* __restrict__ muW1,
                                               float* __restrict__ ws) {
    const int t = threadIdx.x;
    const int br = t >> 6, c = t & 63;
    const float* W  = br ? muW : lvW;
    const float* Gp = br ? muG : lvG;
    const float* Bp = br ? muB : lvB;
    const float inv = 1.f / (float)PTOT;
    const float Eu  = ws[WS_MOM+0]*inv, Ev  = ws[WS_MOM+1]*inv;
    const float Euu = ws[WS_MOM+2]*inv, Evv = ws[WS_MOM+3]*inv, Euv = ws[WS_MOM+4]*inv;
    const float w0 = W[c*2 + 0], w1 = W[c*2 + 1];
    const float m   = w0*Eu + w1*Ev;
    const float e2  = w0*w0*Euu + 2.f*w0*w1*Euv + w1*w1*Evv;
    const float var = e2 - m*m;
    const float rs  = rsqrtf(var + BN_EPSF);
    const float ga = Gp[c], be = Bp[c];
    ws[WS_COEF + (br*64+c)*3 + 0] = w0*rs*ga;
    ws[WS_COEF + (br*64+c)*3 + 1] = w1*rs*ga;
    ws[WS_COEF + (br*64+c)*3 + 2] = be - m*rs*ga;
    // bf16 copy of sd1_W, row-major [br][c][k]
    unsigned short* wb = (unsigned short*)(ws + WS_WB);
    for (int e = t; e < 8192; e += 128) {
        const int brx = e >> 12, r = e & 4095;
        wb[e] = (unsigned short)bf16u((brx ? muW1 : lvW1)[r]);
    }
}

// ---------------- BN2 stats: wave-parallel MFMA h2 recompute (no inner barriers) ----------------
__global__ __launch_bounds__(256) void k_h2stats(const float* __restrict__ p, float* __restrict__ ws) {
    __shared__ float red1[2][4][64];
    __shared__ float red2[2][4][64];
    const int t = threadIdx.x;
    const int bid = blockIdx.x;
    const int b = bid >> 2;
    const int n0 = (bid & 3) * 4096;           // 4096 positions per block
    const float* pk = p + (size_t)b*3*NN + NN;
    const int w = t >> 6, lane = t & 63, g = lane >> 4, col = lane & 15;
    const unsigned short* wbg = (const unsigned short*)(ws + WS_WB);

#pragma unroll 1
    for (int br = 0; br < 2; ++br) {
        float cA[16], cB[16], cC[16];
#pragma unroll
        for (int kt = 0; kt < 2; ++kt)
#pragma unroll
            for (int j = 0; j < 8; ++j) {
                const int i = kt*8 + j, ch = kt*32 + g*8 + j;
                const float* cf = ws + WS_COEF + (br*64 + ch)*3;
                cA[i] = cf[0]; cB[i] = cf[1]; cC[i] = cf[2];
            }
        short8_t a[4][2];
#pragma unroll
        for (int mt = 0; mt < 4; ++mt)
#pragma unroll
            for (int kt = 0; kt < 2; ++kt)
                a[mt][kt] = *(const short8_t*)(wbg + br*4096 + (mt*16+col)*64 + kt*32 + g*8);
        float s1v[16], s2v[16];
#pragma unroll
        for (int i = 0; i < 16; ++i) { s1v[i] = 0.f; s2v[i] = 0.f; }

#pragma unroll 2
        for (int nt = 0; nt < 64; ++nt) {      // wave-owned n-tiles, no barriers
            const int pos = n0 + (nt*4 + w)*16 + col;
            const float u = pk[pos], v = pk[NN + pos];
            union { uint4 u4; short8_t s8; } bf[2];
#pragma unroll
            for (int kt = 0; kt < 2; ++kt) {
                unsigned int dw[4];
#pragma unroll
                for (int q = 0; q < 4; ++q) {
                    const int i0 = kt*8 + q*2;
                    const float h0 = fmaxf(fmaf(cA[i0],   u, fmaf(cB[i0],   v, cC[i0])),   0.f);
                    const float h1 = fmaxf(fmaf(cA[i0+1], u, fmaf(cB[i0+1], v, cC[i0+1])), 0.f);
                    dw[q] = (bf16u(h1) << 16) | bf16u(h0);
                }
                bf[kt].u4 = make_uint4(dw[0], dw[1], dw[2], dw[3]);
            }
            f32x4 acc[4];
#pragma unroll
            for (int mt = 0; mt < 4; ++mt) { f32x4 z = {0.f,0.f,0.f,0.f}; acc[mt] = z; }
#pragma unroll
            for (int mt = 0; mt < 4; ++mt) {
                acc[mt] = __builtin_amdgcn_mfma_f32_16x16x32_bf16(a[mt][0], bf[0].s8, acc[mt], 0,0,0);
                acc[mt] = __builtin_amdgcn_mfma_f32_16x16x32_bf16(a[mt][1], bf[1].s8, acc[mt], 0,0,0);
            }
#pragma unroll
            for (int mt = 0; mt < 4; ++mt)
#pragma unroll
                for (int r = 0; r < 4; ++r) {
                    const int i = mt*4 + r;
                    const float x = acc[mt][r];
                    s1v[i] += x;
                    s2v[i] = fmaf(x, x, s2v[i]);
                }
        }
#pragma unroll
        for (int i = 0; i < 16; ++i) {
#pragma unroll
            for (int off = 1; off <= 8; off <<= 1) {
                s1v[i] += __shfl_xor(s1v[i], off);
                s2v[i] += __shfl_xor(s2v[i], off);
            }
        }
        if (col == 0) {
#pragma unroll
            for (int mt = 0; mt < 4; ++mt)
#pragma unroll
                for (int r = 0; r < 4; ++r) {
                    const int c = mt*16 + g*4 + r;
                    red1[br][w][c] = s1v[mt*4+r];
                    red2[br][w][c] = s2v[mt*4+r];
                }
        }
    }
    __syncthreads();
    if (t < 128) {
        const int br = t >> 6, c = t & 63;
        atomicAdd(&ws[WS_H2S1 + br*64 + c],
                  red1[br][0][c] + red1[br][1][c] + red1[br][2][c] + red1[br][3][c]);
        atomicAdd(&ws[WS_H2S2 + br*64 + c],
                  red2[br][0][c] + red2[br][1][c] + red2[br][2][c] + red2[br][3][c]);
    }
}

// ---------------- finalize BN2 stats ----------------
__global__ __launch_bounds__(128) void k_finstats(float* __restrict__ ws) {
    const int t = threadIdx.x;
    const float inv = 1.f / (float)PTOT;
    const float m2 = ws[WS_H2S1 + t] * inv;
    const float e2 = ws[WS_H2S2 + t] * inv;
    ws[WS_M2  + t] = m2;
    ws[WS_RS2 + t] = rsqrtf(e2 - m2*m2 + BN_EPSF);
}

// ---------------- main pass: wave-parallel MFMA + fused epilogue (no barriers) ----------------
__global__ __launch_bounds__(256) void k_main(
    const float* __restrict__ p,
    const float* __restrict__ lv_sd2W, const float* __restrict__ lv_sd2b,
    const float* __restrict__ mu_sd2W, const float* __restrict__ mu_sd2b,
    const float* __restrict__ ws, float* __restrict__ out)
{
    const int t   = threadIdx.x;
    const int bid = blockIdx.x;
    const int b   = bid >> 4;
    const int n0  = (bid & 15) * 1024;         // 1024 positions per block
    const size_t pb = (size_t)b * 3 * NN;
    const float* pk = p + pb + NN;
    const int w = t >> 6, lane = t & 63, g = lane >> 4, col = lane & 15;
    const unsigned short* wbg = (const unsigned short*)(ws + WS_WB);
    const float sd2b0 = lv_sd2b[0], sd2b1 = mu_sd2b[0];

    float res0[16];
#pragma unroll 1
    for (int br = 0; br < 2; ++br) {
        float cA[16], cB[16], cC[16];
#pragma unroll
        for (int kt = 0; kt < 2; ++kt)
#pragma unroll
            for (int j = 0; j < 8; ++j) {
                const int i = kt*8 + j, ch = kt*32 + g*8 + j;
                const float* cf = ws + WS_COEF + (br*64 + ch)*3;
                cA[i] = cf[0]; cB[i] = cf[1]; cC[i] = cf[2];
            }
        short8_t a[4][2];
#pragma unroll
        for (int mt = 0; mt < 4; ++mt)
#pragma unroll
            for (int kt = 0; kt < 2; ++kt)
                a[mt][kt] = *(const short8_t*)(wbg + br*4096 + (mt*16+col)*64 + kt*32 + g*8);
        float sp[16], tq[16], w2v[16];
#pragma unroll
        for (int mt = 0; mt < 4; ++mt)
#pragma unroll
            for (int r = 0; r < 4; ++r) {
                const int i = mt*4 + r, c = mt*16 + g*4 + r;
                const float fw  = ws[WS_FILMW + br*4096 + b*64 + c];
                const float fb  = ws[WS_FILMB + br*4096 + b*64 + c];
                const float rs2 = ws[WS_RS2 + br*64 + c];
                const float m2  = ws[WS_M2  + br*64 + c];
                const float s = (EPSF + expf(fw)) * rs2;
                sp[i] = s; tq[i] = fb - s*m2;
                w2v[i] = (br ? mu_sd2W : lv_sd2W)[c];
            }

#pragma unroll
        for (int nt = 0; nt < 16; ++nt) {      // wave-owned n-tiles
            const int pos = n0 + (nt*4 + w)*16 + col;
            const float u = pk[pos], v = pk[NN + pos];
            union { uint4 u4; short8_t s8; } bf[2];
#pragma unroll
            for (int kt = 0; kt < 2; ++kt) {
                unsigned int dw[4];
#pragma unroll
                for (int q = 0; q < 4; ++q) {
                    const int i0 = kt*8 + q*2;
                    const float h0 = fmaxf(fmaf(cA[i0],   u, fmaf(cB[i0],   v, cC[i0])),   0.f);
                    const float h1 = fmaxf(fmaf(cA[i0+1], u, fmaf(cB[i0+1], v, cC[i0+1])), 0.f);
                    dw[q] = (bf16u(h1) << 16) | bf16u(h0);
                }
                bf[kt].u4 = make_uint4(dw[0], dw[1], dw[2], dw[3]);
            }
            f32x4 acc[4];
#pragma unroll
            for (int mt = 0; mt < 4; ++mt) { f32x4 z = {0.f,0.f,0.f,0.f}; acc[mt] = z; }
#pragma unroll
            for (int mt = 0; mt < 4; ++mt) {
                acc[mt] = __builtin_amdgcn_mfma_f32_16x16x32_bf16(a[mt][0], bf[0].s8, acc[mt], 0,0,0);
                acc[mt] = __builtin_amdgcn_mfma_f32_16x16x32_bf16(a[mt][1], bf[1].s8, acc[mt], 0,0,0);
            }
            float po = 0.f;
#pragma unroll
            for (int mt = 0; mt < 4; ++mt)
#pragma unroll
                for (int r = 0; r < 4; ++r) {
                    const int i = mt*4 + r;
                    const float hf = fmaf(acc[mt][r], sp[i], tq[i]);
                    po = fmaf(fmaxf(hf, 0.f), w2v[i], po);
                }
            po += __shfl_xor(po, 16);
            po += __shfl_xor(po, 32);
            if (br == 0) {
                res0[nt] = po;
            } else {
                const float ol = res0[nt] + sd2b0;
                const float om = po + sd2b1;
                const float lw = ol / (1.f + fabsf(ol));
                const float sc = sqrtf(EPSF + expf(lw));
                if (lane < 16) {
                    const size_t nix = pb + pos;
                    const float x0 = p[nix];
                    out[nix]          = fmaf(sc, x0, om);
                    out[OFF_MU + nix] = om;
                    out[OFF_LV + nix] = lw;
                }
            }
        }
    }
    // channels 1,2 pass-through (coalesced, all 256 threads)
    const float S1 = sqrtf(1.f + EPSF);
#pragma unroll
    for (int e = 0; e < 4; ++e) {
        const int j = e*256 + t;
        const size_t ix1 = pb + (size_t)NN + n0 + j;
        const size_t ix2 = pb + (size_t)2*NN + n0 + j;
        const float uu = p[ix1], vv = p[ix2];
        out[ix1]          = S1 * uu;
        out[OFF_MU + ix1] = 0.f;
        out[OFF_LV + ix1] = 0.f;
        out[ix2]          = S1 * vv;
        out[OFF_MU + ix2] = 0.f;
        out[OFF_LV + ix2] = 0.f;
    }
}

extern "C" void kernel_launch(void* const* d_in, const int* in_sizes, int n_in,
                              void* d_out, int out_size, void* d_ws, size_t ws_size,
                              hipStream_t stream) {
    (void)in_sizes; (void)n_in; (void)out_size; (void)ws_size;
    const float* p = (const float*)d_in[0];
    const float* g = (const float*)d_in[1];
#define IN(i) ((const float*)d_in[i])
    float* ws  = (float*)d_ws;
    float* out = (float*)d_out;

    hipMemsetAsync(d_ws, 0, WS_ZERO_FLOATS * sizeof(float), stream);

    // combos: 0=lv_cw 1=lv_cb 2=mu_cw 3=mu_cb
    hipLaunchKernelGGL(k_filmA, dim3(4, 8), dim3(256), 0, stream,
                       g, IN(6), IN(11), IN(22), IN(27), ws);
    hipLaunchKernelGGL(k_filmB, dim3(4),    dim3(256), 0, stream,
                       IN(7),  IN(8),  IN(9),  IN(10),
                       IN(12), IN(13), IN(14), IN(15),
                       IN(23), IN(24), IN(25), IN(26),
                       IN(28), IN(29), IN(30), IN(31),
                       ws);
    hipLaunchKernelGGL(k_moments, dim3(512), dim3(256), 0, stream, p, ws);
    hipLaunchKernelGGL(k_coef2,   dim3(1),   dim3(128), 0, stream,
                       IN(2), IN(3), IN(4), IN(18), IN(19), IN(20), IN(5), IN(21), ws);
    hipLaunchKernelGGL(k_h2stats, dim3(256), dim3(256), 0, stream, p, ws);
    hipLaunchKernelGGL(k_finstats, dim3(1),  dim3(128), 0, stream, ws);
    hipLaunchKernelGGL(k_main,    dim3(1024), dim3(256), 0, stream,
                       p, IN(16), IN(17), IN(32), IN(33), ws, out);
#undef IN
}